// Round 9
// baseline (857.583 us; speedup 1.0000x reference)
//
#include <hip/hip_runtime.h>
#include <math.h>

#define N_NODES 16384
#define N_EDGES 131072
#define N_MOLS 512
#define HDIM 256
#define NLAYER 3
#define NRBF 50
#define CUT 5.0f
#define HH (HDIM*HDIM)

typedef unsigned short u16;
typedef __attribute__((ext_vector_type(8))) short short8v;
typedef __attribute__((ext_vector_type(4))) float f32x4;
typedef __attribute__((ext_vector_type(4))) unsigned short u16x4;
typedef __attribute__((ext_vector_type(8))) unsigned short u16x8;

__device__ __forceinline__ float softplusf(float x){ return fmaxf(x,0.f)+log1pf(expf(-fabsf(x))); }
__device__ __forceinline__ float siluf(float x){ return x/(1.f+expf(-x)); }
__device__ __forceinline__ float bf2f(u16 u){ union{unsigned int i; float f;}v; v.i=((unsigned int)u)<<16; return v.f; }
__device__ __forceinline__ u16 f2bf(float f){ union{float f; unsigned int i;}v; v.f=f; unsigned int r = v.i + 0x7FFFu + ((v.i>>16)&1u); return (u16)(r>>16); }

__device__ __forceinline__ void gload_lds16(const void* g, void* l){
  __builtin_amdgcn_global_load_lds((const __attribute__((address_space(1))) unsigned int*)g,
                                   (__attribute__((address_space(3))) unsigned int*)l, 16, 0, 0);
}

// ---------------- CSR build ----------------
__global__ void k_hist(const int* __restrict__ dst, int* __restrict__ cnt){
  int e = blockIdx.x*256 + threadIdx.x;
  if(e < N_EDGES) atomicAdd(&cnt[dst[e]], 1);
}

__global__ __launch_bounds__(1024) void k_scan(const int* __restrict__ cnt,
                                               int* __restrict__ rowptr,
                                               int* __restrict__ cursor){
  __shared__ int part[1024];
  int tid = threadIdx.x;
  int base = tid*16;
  int loc[16]; int s=0;
  #pragma unroll
  for(int i=0;i<16;i++){ loc[i]=s; s+=cnt[base+i]; }
  part[tid]=s; __syncthreads();
  for(int off=1; off<1024; off<<=1){
    int v = (tid>=off)? part[tid-off] : 0;
    __syncthreads();
    part[tid] += v;
    __syncthreads();
  }
  int pre = (tid==0)?0:part[tid-1];
  #pragma unroll
  for(int i=0;i<16;i++){ int v = pre+loc[i]; rowptr[base+i]=v; cursor[base+i]=v; }
  if(tid==1023) rowptr[N_NODES]=part[1023];
}

__global__ void k_scatter(const int* __restrict__ dst, const int* __restrict__ src,
                          int* __restrict__ cursor,
                          int* __restrict__ perm, int* __restrict__ srcp){
  int e = blockIdx.x*256+threadIdx.x;
  if(e<N_EDGES){
    int p = atomicAdd(&cursor[dst[e]],1);
    perm[p]=e;
    srcp[p]=src[e];
  }
}

// ---------------- RBF in CSR order (bf16, padded to 64) ----------------
__global__ void k_rbf(const float* __restrict__ dist, const int* __restrict__ perm,
                      u16* __restrict__ rbfp){
  int gid = blockIdx.x*256+threadIdx.x;
  int i = gid>>6, r = gid&63;
  int e = perm[i];
  u16 o = 0;
  if(r<NRBF){
    float d = dist[e];
    float env = 0.5f*(cosf(3.14159265358979f*d/CUT)+1.f) * (d<CUT ? 1.f:0.f);
    float c = CUT*(float)r/(float)(NRBF-1);
    float u = (d - c)/(CUT/(float)NRBF);
    o = f2bf(expf(-0.5f*u*u)*env);
  }
  rbfp[(size_t)i*64+r] = o;
}

// ---------------- weight transpose+convert: W[K][256] f32 -> Wt[256][dK] bf16 ----------------
struct WDesc { const float* src; u16* dst; int K; int dK; };
struct WArgs { WDesc d[28]; };
__global__ __launch_bounds__(256) void k_wconv(WArgs a){
  WDesc w = a.d[blockIdx.x];
  int t = blockIdx.y;
  int ky = t >> 3, nx = t & 7;
  if(ky*32 >= w.dK) return;
  __shared__ float tile[32][33];
  int tid = threadIdx.x;
  int kk = tid >> 3, n4 = (tid & 7)*4;
  int k = ky*32 + kk;
  float4 v = {0.f,0.f,0.f,0.f};
  if(k < w.K) v = *(const float4*)(w.src + (size_t)k*HDIM + nx*32 + n4);
  tile[kk][n4+0]=v.x; tile[kk][n4+1]=v.y; tile[kk][n4+2]=v.z; tile[kk][n4+3]=v.w;
  __syncthreads();
  int nn = tid >> 3, k4 = (tid & 7)*4;
  u16x4 o;
  #pragma unroll
  for(int j=0;j<4;j++) o[j] = f2bf(tile[k4+j][nn]);
  *(u16x4*)(w.dst + (size_t)(nx*32+nn)*w.dK + ky*32 + k4) = o;
}

// ---------------- embedding ----------------
__global__ void k_embed(const float* __restrict__ at, const float* __restrict__ co,
                        const float* __restrict__ Wm, const float* __restrict__ bm,
                        const float* __restrict__ Wp, const float* __restrict__ bp,
                        float* __restrict__ mag, float* __restrict__ ph,
                        u16* __restrict__ magb, u16* __restrict__ phb){
  int n = blockIdx.x; int h = threadIdx.x;
  __shared__ float x[8];
  if(threadIdx.x<5) x[threadIdx.x] = at[n*5+threadIdx.x];
  else if(threadIdx.x<8) x[threadIdx.x] = co[n*3+threadIdx.x-5];
  __syncthreads();
  float tm=bm[h], tp=bp[h];
  #pragma unroll
  for(int i=0;i<8;i++){ tm = fmaf(x[i],Wm[i*HDIM+h],tm); tp = fmaf(x[i],Wp[i*HDIM+h],tp); }
  size_t idx = (size_t)n*HDIM+h;
  float m = softplusf(tm);
  float p = 3.14159265358979f*tanhf(tp);
  mag[idx]=m; ph[idx]=p; magb[idx]=f2bf(m); phb[idx]=f2bf(p);
}

// ======== full-N GEMM: 512 thr, BM=128, BN=256(whole width), BK=64 ========
// waves 2(M)x4(N), wave tile 64x64. A read ONCE per block. XOR chunk swizzle both sides.
// MODE 1: silu(x+bias)->bf16. 3: f32 = x+bias. 4: f32 = x+bias+bf16addend[row*512+aoff+col].
template<int MODE>
__device__ __forceinline__ void gemm_fullN(const u16* __restrict__ A,
                                           const u16* __restrict__ Bt,
                                           const float* __restrict__ bias,
                                           void* __restrict__ outp, int K,
                                           const u16* __restrict__ add=nullptr, int aoff=0){
  __shared__ __align__(16) u16 As[128*64];
  __shared__ __align__(16) u16 Bs[256*64];
  int tid = threadIdx.x;
  int lane = tid & 63, wid = tid >> 6;
  int wm = wid & 1, wn = wid >> 1;
  int m0 = blockIdx.y * 128;
  const size_t Kb = (size_t)K*2;
  f32x4 acc[4][4] = {};
  for(int k0=0;k0<K;k0+=64){
    #pragma unroll
    for(int it=0; it<2; it++){
      int ci = it*512 + tid;
      int row = ci>>3, cl = ci&7;
      int csw = cl ^ (row&7);
      size_t go = (size_t)(m0+row)*Kb + (size_t)k0*2 + csw*16;
      gload_lds16((const char*)A+go, (char*)As + it*8192 + wid*1024);
    }
    #pragma unroll
    for(int it=0; it<4; it++){
      int ci = it*512 + tid;
      int row = ci>>3, cl = ci&7;
      int csw = cl ^ (row&7);
      size_t go = (size_t)row*Kb + (size_t)k0*2 + csw*16;
      gload_lds16((const char*)Bt+go, (char*)Bs + it*8192 + wid*1024);
    }
    __syncthreads();
    #pragma unroll
    for(int ks=0;ks<2;ks++){
      short8v a[4], b[4];
      #pragma unroll
      for(int fm=0;fm<4;fm++){
        int m = wm*64 + fm*16 + (lane&15);
        int ch = (ks*4 + (lane>>4)) ^ (m&7);
        a[fm] = *(const short8v*)&As[m*64 + ch*8];
      }
      #pragma unroll
      for(int fn=0;fn<4;fn++){
        int n = wn*64 + fn*16 + (lane&15);
        int ch = (ks*4 + (lane>>4)) ^ (n&7);
        b[fn] = *(const short8v*)&Bs[n*64 + ch*8];
      }
      #pragma unroll
      for(int fm=0;fm<4;fm++)
        #pragma unroll
        for(int fn=0;fn<4;fn++)
          acc[fm][fn] = __builtin_amdgcn_mfma_f32_16x16x32_bf16(a[fm], b[fn], acc[fm][fn],0,0,0);
    }
    __syncthreads();
  }
  int ro=(lane>>4)*4, co=lane&15;
  #pragma unroll
  for(int fm=0;fm<4;fm++){
    #pragma unroll
    for(int fn=0;fn<4;fn++){
      int col = wn*64 + fn*16 + co;
      float bv = bias ? bias[col] : 0.f;
      #pragma unroll
      for(int r=0;r<4;r++){
        int row = m0 + wm*64 + fm*16 + ro + r;
        float v = acc[fm][fn][r] + bv;
        size_t ci = (size_t)row*256 + col;
        if(MODE==1) ((u16*)outp)[ci] = f2bf(siluf(v));
        else if(MODE==4) ((float*)outp)[ci] = v + bf2f(add[(size_t)row*512 + aoff + col]);
        else ((float*)outp)[ci] = v;
      }
    }
  }
}

__global__ __launch_bounds__(512) void k_gemm_gate(const u16* __restrict__ rbfp,
                                                   const u16* __restrict__ Wt,
                                                   const float* __restrict__ be,
                                                   u16* __restrict__ gate){
  gemm_fullN<1>(rbfp, Wt, be, gate, 64);
}
struct MpArgs { const u16* A[2]; const u16* Wt[2]; const float* b[2]; float* C[2]; const u16* add; };
__global__ __launch_bounds__(512) void k_gemm_mp(MpArgs a){
  int z = blockIdx.z;
  gemm_fullN<4>(a.A[z], a.Wt[z], a.b[z], a.C[z], HDIM, a.add, z==0?0:256);
}
__global__ __launch_bounds__(512) void k_gemm_proj(const u16* __restrict__ Ab,
                                                   const u16* __restrict__ Wt,
                                                   const float* __restrict__ b,
                                                   float* __restrict__ C){
  gemm_fullN<3>(Ab, Wt, b, C, HDIM);
}

// ======== full-N PAIR GEMM for QKV (mag & ph together) + sincos epilogue ========
struct Qkv3Args { const u16* Wm[3]; const u16* Wp[3]; u16* qpk; u16* kvpk; };
__global__ __launch_bounds__(512) void k_gemm_qkv3(const u16* __restrict__ magb,
                                                   const u16* __restrict__ phb,
                                                   Qkv3Args a){
  __shared__ __align__(16) u16 Ams[128*64];
  __shared__ __align__(16) u16 Aps[128*64];
  __shared__ __align__(16) u16 Bms[256*64];
  __shared__ __align__(16) u16 Bps[256*64];
  int z = blockIdx.z;
  const u16* Wmz = a.Wm[z];
  const u16* Wpz = a.Wp[z];
  int tid = threadIdx.x;
  int lane = tid & 63, wid = tid >> 6;
  int wm = wid & 1, wn = wid >> 1;
  int m0 = blockIdx.y * 128;
  const size_t Kb = 512;  // K=256 bf16
  f32x4 accm[4][4] = {}, accp[4][4] = {};
  for(int k0=0;k0<256;k0+=64){
    #pragma unroll
    for(int it=0; it<2; it++){
      int ci = it*512 + tid;
      int row = ci>>3, cl = ci&7;
      int csw = cl ^ (row&7);
      size_t go = (size_t)(m0+row)*Kb + (size_t)k0*2 + csw*16;
      gload_lds16((const char*)magb+go, (char*)Ams + it*8192 + wid*1024);
      gload_lds16((const char*)phb +go, (char*)Aps + it*8192 + wid*1024);
    }
    #pragma unroll
    for(int it=0; it<4; it++){
      int ci = it*512 + tid;
      int row = ci>>3, cl = ci&7;
      int csw = cl ^ (row&7);
      size_t go = (size_t)row*Kb + (size_t)k0*2 + csw*16;
      gload_lds16((const char*)Wmz+go, (char*)Bms + it*8192 + wid*1024);
      gload_lds16((const char*)Wpz+go, (char*)Bps + it*8192 + wid*1024);
    }
    __syncthreads();
    #pragma unroll
    for(int ks=0;ks<2;ks++){
      short8v am[4], ap[4], bm_[4], bp_[4];
      #pragma unroll
      for(int fm=0;fm<4;fm++){
        int m = wm*64 + fm*16 + (lane&15);
        int ch = (ks*4 + (lane>>4)) ^ (m&7);
        am[fm] = *(const short8v*)&Ams[m*64 + ch*8];
        ap[fm] = *(const short8v*)&Aps[m*64 + ch*8];
      }
      #pragma unroll
      for(int fn=0;fn<4;fn++){
        int n = wn*64 + fn*16 + (lane&15);
        int ch = (ks*4 + (lane>>4)) ^ (n&7);
        bm_[fn] = *(const short8v*)&Bms[n*64 + ch*8];
        bp_[fn] = *(const short8v*)&Bps[n*64 + ch*8];
      }
      #pragma unroll
      for(int fm=0;fm<4;fm++)
        #pragma unroll
        for(int fn=0;fn<4;fn++){
          accm[fm][fn] = __builtin_amdgcn_mfma_f32_16x16x32_bf16(am[fm], bm_[fn], accm[fm][fn],0,0,0);
          accp[fm][fn] = __builtin_amdgcn_mfma_f32_16x16x32_bf16(ap[fm], bp_[fn], accp[fm][fn],0,0,0);
        }
    }
    __syncthreads();
  }
  int ro=(lane>>4)*4, co=lane&15;
  #pragma unroll
  for(int fm=0;fm<4;fm++){
    #pragma unroll
    for(int fn=0;fn<4;fn++){
      int col = wn*64 + fn*16 + co;
      #pragma unroll
      for(int r=0;r<4;r++){
        int row = m0 + wm*64 + fm*16 + ro + r;
        float mv = accm[fm][fn][r];
        float pv = accp[fm][fn][r];
        u16 o0, o1;
        if(z<2){
          float sn, cs;
          __sincosf(pv, &sn, &cs);
          o0 = f2bf(mv*cs); o1 = f2bf(mv*sn);
        } else {
          o0 = f2bf(mv); o1 = f2bf(pv);
        }
        u16* base = (z==0) ? (a.qpk + (size_t)row*512)
                           : (a.kvpk + (size_t)row*1024 + (z==2 ? 512 : 0));
        base[col] = o0;
        base[col+256] = o1;
      }
    }
  }
}

// ---------------- fused attention v4: 4 edge-streams/wave, 16 lanes x 16 ch ----------------
__global__ __launch_bounds__(256) void k_attn_fused(
    const int* __restrict__ rowptr, const int* __restrict__ srcp,
    const u16* __restrict__ qpack, const u16* __restrict__ kvpack,
    const u16* __restrict__ rbfp,
    const float* __restrict__ We, const float* __restrict__ be,
    u16* __restrict__ npack)
{
  int wid = threadIdx.x >> 6, lane = threadIdx.x & 63;
  int gid = lane >> 4, l = lane & 15;
  int d = blockIdx.x*4 + wid;
  int b = rowptr[d], e = rowptr[d+1];
  const u16* qb = qpack + (size_t)d*512 + l*16;
  u16x8 qc0 = *(const u16x8*)qb;
  u16x8 qc1 = *(const u16x8*)(qb+8);
  u16x8 qs0 = *(const u16x8*)(qb+256);
  u16x8 qs1 = *(const u16x8*)(qb+264);
  float qcf[16], qsf[16];
  #pragma unroll
  for(int j=0;j<8;j++){
    qcf[j]=bf2f(qc0[j]); qcf[j+8]=bf2f(qc1[j]);
    qsf[j]=bf2f(qs0[j]); qsf[j+8]=bf2f(qs1[j]);
  }
  float Wef[4];
  #pragma unroll
  for(int k=0;k<4;k++) Wef[k] = (l*4+k < NRBF) ? We[l*4+k] : 0.f;
  float be0 = be[0];
  float z = 0.f;
  float avm[16], avp[16];
  #pragma unroll
  for(int j=0;j<16;j++){ avm[j]=0.f; avp[j]=0.f; }
  for(int i = b + gid; i < e; i += 4){
    int s = srcp[i];
    const u16* kb = kvpack + (size_t)s*1024 + l*16;
    u16x8 kc0 = *(const u16x8*)kb;
    u16x8 kc1 = *(const u16x8*)(kb+8);
    u16x8 ks0 = *(const u16x8*)(kb+256);
    u16x8 ks1 = *(const u16x8*)(kb+264);
    u16x8 vm0 = *(const u16x8*)(kb+512);
    u16x8 vm1 = *(const u16x8*)(kb+520);
    u16x8 vp0 = *(const u16x8*)(kb+768);
    u16x8 vp1 = *(const u16x8*)(kb+776);
    u16x4 rb4 = *(const u16x4*)(rbfp + (size_t)i*64 + l*4);
    float p = 0.f;
    #pragma unroll
    for(int j=0;j<8;j++){
      p = fmaf(qcf[j],   bf2f(kc0[j]), p);
      p = fmaf(qcf[j+8], bf2f(kc1[j]), p);
      p = fmaf(qsf[j],   bf2f(ks0[j]), p);
      p = fmaf(qsf[j+8], bf2f(ks1[j]), p);
    }
    float t = p*0.0625f;
    #pragma unroll
    for(int k=0;k<4;k++) t = fmaf(bf2f(rb4[k]), Wef[k], t);
    #pragma unroll
    for(int off=8; off; off>>=1) t += __shfl_xor(t, off, 64);
    float w = __expf(t + be0);   // scores O(1): softmax shift-invariant
    z += w;
    #pragma unroll
    for(int j=0;j<8;j++){
      avm[j]   = fmaf(w, bf2f(vm0[j]), avm[j]);
      avm[j+8] = fmaf(w, bf2f(vm1[j]), avm[j+8]);
      avp[j]   = fmaf(w, bf2f(vp0[j]), avp[j]);
      avp[j+8] = fmaf(w, bf2f(vp1[j]), avp[j+8]);
    }
  }
  z += __shfl_xor(z, 16, 64);
  z += __shfl_xor(z, 32, 64);
  #pragma unroll
  for(int j=0;j<16;j++){
    avm[j] += __shfl_xor(avm[j], 16, 64);
    avm[j] += __shfl_xor(avm[j], 32, 64);
    avp[j] += __shfl_xor(avp[j], 16, 64);
    avp[j] += __shfl_xor(avp[j], 32, 64);
  }
  if(gid==0){
    float inv = 1.f/(z + 1e-9f);
    u16x8 m0, m1, p0, p1;
    #pragma unroll
    for(int j=0;j<8;j++){
      m0[j]=f2bf(avm[j]*inv); m1[j]=f2bf(avm[j+8]*inv);
      p0[j]=f2bf(avp[j]*inv); p1[j]=f2bf(avp[j+8]*inv);
    }
    u16* nb = npack + (size_t)d*512 + l*16;
    *(u16x8*)nb = m0;       *(u16x8*)(nb+8)   = m1;
    *(u16x8*)(nb+256) = p0; *(u16x8*)(nb+264) = p1;
  }
}

// ---------------- message passing aggregation v4 (4 streams, 16 lanes x 16 ch) ----------------
__global__ __launch_bounds__(256) void k_mp_agg(const int* __restrict__ rowptr,
                         const int* __restrict__ srcp, const u16* __restrict__ gate,
                         const u16* __restrict__ npack,
                         u16* __restrict__ aggm, u16* __restrict__ aggp){
  int wid = threadIdx.x >> 6, lane = threadIdx.x & 63;
  int gid = lane >> 4, l = lane & 15;
  int n = blockIdx.x*4 + wid;
  int b = rowptr[n], e = rowptr[n+1];
  float am[16], ap[16];
  #pragma unroll
  for(int j=0;j<16;j++){ am[j]=0.f; ap[j]=0.f; }
  for(int i = b + gid; i < e; i += 4){
    int s = srcp[i];
    const u16* gb = gate + (size_t)i*256 + l*16;
    u16x8 g0 = *(const u16x8*)gb;
    u16x8 g1 = *(const u16x8*)(gb+8);
    const u16* nb = npack + (size_t)s*512 + l*16;
    u16x8 m0 = *(const u16x8*)nb;
    u16x8 m1 = *(const u16x8*)(nb+8);
    u16x8 p0 = *(const u16x8*)(nb+256);
    u16x8 p1 = *(const u16x8*)(nb+264);
    #pragma unroll
    for(int j=0;j<8;j++){
      float ga = bf2f(g0[j]), gb2 = bf2f(g1[j]);
      am[j]   = fmaf(ga,  bf2f(m0[j]), am[j]);
      am[j+8] = fmaf(gb2, bf2f(m1[j]), am[j+8]);
      ap[j]   = fmaf(ga,  bf2f(p0[j]), ap[j]);
      ap[j+8] = fmaf(gb2, bf2f(p1[j]), ap[j+8]);
    }
  }
  #pragma unroll
  for(int j=0;j<16;j++){
    am[j] += __shfl_xor(am[j], 16, 64);
    am[j] += __shfl_xor(am[j], 32, 64);
    ap[j] += __shfl_xor(ap[j], 16, 64);
    ap[j] += __shfl_xor(ap[j], 32, 64);
  }
  if(gid==0){
    u16x8 a0, a1, b0, b1;
    #pragma unroll
    for(int j=0;j<8;j++){
      a0[j]=f2bf(am[j]); a1[j]=f2bf(am[j+8]);
      b0[j]=f2bf(ap[j]); b1[j]=f2bf(ap[j+8]);
    }
    size_t o = (size_t)n*256 + l*16;
    *(u16x8*)(aggm + o) = a0; *(u16x8*)(aggm + o + 8) = a1;
    *(u16x8*)(aggp + o) = b0; *(u16x8*)(aggp + o + 8) = b1;
  }
}

// ---------------- residual + LayerNorm (LAST fuses mag*cos(ph) projection input) ----------------
template<int LAST>
__global__ __launch_bounds__(256) void k_resid_ln(const float* __restrict__ nmag, const float* __restrict__ nph,
                           float* __restrict__ mag, float* __restrict__ ph,
                           u16* __restrict__ magb, u16* __restrict__ phb,
                           u16* __restrict__ tcosb,
                           const float* __restrict__ g, const float* __restrict__ b){
  int n = blockIdx.x, tid = threadIdx.x;
  size_t idx = (size_t)n*HDIM+tid;
  float t = nmag[idx] + mag[idx];
  float s1=t, s2=t*t;
  #pragma unroll
  for(int off=32; off; off>>=1){ s1 += __shfl_down(s1,off,64); s2 += __shfl_down(s2,off,64); }
  __shared__ float w1[4], w2[4], bc[2];
  int wid = tid>>6, lane = tid&63;
  if(lane==0){ w1[wid]=s1; w2[wid]=s2; }
  __syncthreads();
  if(tid==0){
    float a=w1[0]+w1[1]+w1[2]+w1[3];
    float q=w2[0]+w2[1]+w2[2]+w2[3];
    float mu = a*(1.f/HDIM);
    float var = q*(1.f/HDIM) - mu*mu;
    bc[0]=mu; bc[1]=rsqrtf(var+1e-5f);
  }
  __syncthreads();
  float mu=bc[0], rs=bc[1];
  float ln = (t-mu)*rs*g[tid]+b[tid];
  float p2 = nph[idx] + ph[idx];
  if(LAST){
    tcosb[idx] = f2bf(ln*__cosf(p2));
  } else {
    mag[idx] = ln; magb[idx] = f2bf(ln);
    ph[idx] = p2; phb[idx] = f2bf(p2);
  }
}

// ---------------- pooling ----------------
__global__ void k_pool(const float* __restrict__ arepr, const int* __restrict__ n2m,
                       float* __restrict__ spool, float* __restrict__ cntf){
  int gid = blockIdx.x*256+threadIdx.x;
  int n = gid>>8, h = gid&255;
  int m = n2m[n];
  atomicAdd(&spool[(size_t)m*HDIM+h], arepr[(size_t)n*HDIM+h]);
  if(h==0) atomicAdd(&cntf[m], 1.f);
}

// ---------------- head MLP ----------------
__global__ __launch_bounds__(256) void k_head(const float* __restrict__ spool, const float* __restrict__ cntf,
                       const float* __restrict__ W1, const float* __restrict__ b1,
                       const float* __restrict__ W2, const float* __restrict__ b2,
                       const float* __restrict__ W3, const float* __restrict__ b3,
                       float* __restrict__ out){
  __shared__ float smol[2*HDIM];
  __shared__ float sh1[HDIM];
  __shared__ float sh2[HDIM/2];
  int m = blockIdx.x, tid = threadIdx.x;
  float sv = spool[(size_t)m*HDIM+tid];
  float c = cntf[m];
  smol[tid] = sv/fmaxf(c,1.f);
  smol[HDIM+tid] = sv;
  __syncthreads();
  float a = b1[tid];
  for(int i=0;i<2*HDIM;i++) a = fmaf(smol[i], W1[i*HDIM+tid], a);
  sh1[tid] = siluf(a);
  __syncthreads();
  if(tid<128){
    float a2 = b2[tid];
    for(int i=0;i<HDIM;i++) a2 = fmaf(sh1[i], W2[i*128+tid], a2);
    sh2[tid] = siluf(a2);
  }
  __syncthreads();
  if(tid<64){
    float p = sh2[tid]*W3[tid] + sh2[tid+64]*W3[tid+64];
    #pragma unroll
    for(int off=32; off; off>>=1) p += __shfl_down(p,off,64);
    if(tid==0) out[m] = p + b3[0];
  }
}

extern "C" void kernel_launch(void* const* d_in, const int* in_sizes, int n_in,
                              void* d_out, int out_size, void* d_ws, size_t ws_size,
                              hipStream_t stream){
  const float* atom_types = (const float*)d_in[0];
  const float* coords     = (const float*)d_in[1];
  const float* edge_dist  = (const float*)d_in[2];
  const int*   edge_index = (const int*)d_in[3];
  const int*   node2mol   = (const int*)d_in[4];
  const float* emb_Wm = (const float*)d_in[5];
  const float* emb_bm = (const float*)d_in[6];
  const float* emb_Wp = (const float*)d_in[7];
  const float* emb_bp = (const float*)d_in[8];
  const float* attn_Wqm = (const float*)d_in[9];
  const float* attn_Wkm = (const float*)d_in[10];
  const float* attn_Wvm = (const float*)d_in[11];
  const float* attn_Wqp = (const float*)d_in[12];
  const float* attn_Wkp = (const float*)d_in[13];
  const float* attn_Wvp = (const float*)d_in[14];
  const float* attn_We  = (const float*)d_in[15];
  const float* attn_be  = (const float*)d_in[16];
  const float* mp_We = (const float*)d_in[17];
  const float* mp_be = (const float*)d_in[18];
  const float* mp_Wm = (const float*)d_in[19];
  const float* mp_bm = (const float*)d_in[20];
  const float* mp_Wp = (const float*)d_in[21];
  const float* mp_bp = (const float*)d_in[22];
  const float* ln_g = (const float*)d_in[23];
  const float* ln_b = (const float*)d_in[24];
  const float* proj_W = (const float*)d_in[25];
  const float* proj_b = (const float*)d_in[26];
  const float* head_W1 = (const float*)d_in[27];
  const float* head_b1 = (const float*)d_in[28];
  const float* head_W2 = (const float*)d_in[29];
  const float* head_b2 = (const float*)d_in[30];
  const float* head_W3 = (const float*)d_in[31];
  const float* head_b3 = (const float*)d_in[32];
  float* out = (float*)d_out;

  float* ws = (float*)d_ws;
  const size_t NH = (size_t)N_NODES*HDIM;
  size_t o = 0;
  float* mag = ws + o; o += NH;
  float* ph  = ws + o; o += NH;
  float* nmag= ws + o; o += NH;
  float* nph = ws + o; o += NH;
  float* spool = ws + o; o += (size_t)N_MOLS*HDIM;
  float* cntf  = ws + o; o += N_MOLS;
  int* rowptr = (int*)(ws + o); o += N_NODES+1;
  int* cnt    = (int*)(ws + o); o += N_NODES;
  int* cursor = (int*)(ws + o); o += N_NODES;
  int* perm   = (int*)(ws + o); o += N_EDGES;
  int* srcp   = (int*)(ws + o); o += N_EDGES + 1;   // +1 keeps 8B alignment after
  u16* magb = (u16*)(ws + o); o += NH/2;
  u16* phb  = (u16*)(ws + o); o += NH/2;
  u16* aggmb= (u16*)(ws + o); o += NH/2;
  u16* aggpb= (u16*)(ws + o); o += NH/2;
  u16* npack= (u16*)(ws + o); o += NH;                        // [N][512] bf16 (mag|ph)
  u16* rbfp = (u16*)(ws + o); o += (size_t)N_EDGES*32;        // [E][64] bf16, CSR order
  u16* qpack= (u16*)(ws + o); o += NH;                        // [N][512] bf16 (qc|qs)
  u16* kvpack=(u16*)(ws + o); o += 2*NH;                      // [N][1024] bf16 (kc|ks|vm|vp)
  o += NH;                                                    // pad: gatep tail
  u16* wt   = (u16*)(ws + o); o += (25*(size_t)HH + 3*HDIM*64)/2;
  u16* gatep = qpack;      // [E][256] bf16 CSR order; aliases qpack+kvpack+pad (disjoint lifetime)
  float* arepr = nmag;     // free after last resid_ln
  u16* tcosb = aggmb;      // free after last mp gemm

  const int* src = edge_index;
  const int* dst = edge_index + N_EDGES;

  // ---- weight convert/transpose descriptors ----
  WArgs wa;
  for(int l=0;l<NLAYER;l++){
    const float* srcs[6] = {attn_Wqm+(size_t)l*HH, attn_Wkm+(size_t)l*HH, attn_Wvm+(size_t)l*HH,
                            attn_Wqp+(size_t)l*HH, attn_Wkp+(size_t)l*HH, attn_Wvp+(size_t)l*HH};
    for(int j=0;j<6;j++){ wa.d[l*6+j] = { srcs[j], wt + (size_t)(l*6+j)*HH, HDIM, HDIM }; }
    wa.d[18+l] = { mp_Wm+(size_t)l*HH, wt + (size_t)(18+l)*HH, HDIM, HDIM };
    wa.d[21+l] = { mp_Wp+(size_t)l*HH, wt + (size_t)(21+l)*HH, HDIM, HDIM };
    wa.d[25+l] = { mp_We+(size_t)l*NRBF*HDIM, wt + (size_t)25*HH + (size_t)l*HDIM*64, NRBF, 64 };
  }
  wa.d[24] = { proj_W, wt + (size_t)24*HH, HDIM, HDIM };

  hipMemsetAsync(cnt, 0, N_NODES*sizeof(int), stream);
  k_hist<<<N_EDGES/256,256,0,stream>>>(dst, cnt);
  k_scan<<<1,1024,0,stream>>>(cnt, rowptr, cursor);
  k_scatter<<<N_EDGES/256,256,0,stream>>>(dst, src, cursor, perm, srcp);
  k_wconv<<<dim3(28,64),256,0,stream>>>(wa);
  k_rbf<<<(N_EDGES*64)/256,256,0,stream>>>(edge_dist, perm, rbfp);
  k_embed<<<N_NODES,256,0,stream>>>(atom_types, coords, emb_Wm, emb_bm, emb_Wp, emb_bp,
                                    mag, ph, magb, phb);

  for(int l=0;l<NLAYER;l++){
    Qkv3Args qa;
    qa.Wm[0] = wt + (size_t)(l*6+0)*HH;  // Wqm
    qa.Wm[1] = wt + (size_t)(l*6+1)*HH;  // Wkm
    qa.Wm[2] = wt + (size_t)(l*6+2)*HH;  // Wvm
    qa.Wp[0] = wt + (size_t)(l*6+3)*HH;  // Wqp
    qa.Wp[1] = wt + (size_t)(l*6+4)*HH;  // Wkp
    qa.Wp[2] = wt + (size_t)(l*6+5)*HH;  // Wvp
    qa.qpk = qpack; qa.kvpk = kvpack;
    k_gemm_qkv3<<<dim3(1,N_NODES/128,3),512,0,stream>>>(magb, phb, qa);
    k_attn_fused<<<N_NODES/4,256,0,stream>>>(rowptr, srcp, qpack, kvpack,
                                             rbfp, attn_We+(size_t)l*NRBF, attn_be+l,
                                             npack);
    k_gemm_gate<<<dim3(1,N_EDGES/128),512,0,stream>>>(rbfp, wt + (size_t)25*HH + (size_t)l*HDIM*64,
                                                      mp_be+(size_t)l*HDIM, gatep);
    k_mp_agg<<<N_NODES/4,256,0,stream>>>(rowptr, srcp, gatep, npack, aggmb, aggpb);
    MpArgs ma;
    ma.A[0]=aggmb; ma.A[1]=aggpb;
    ma.Wt[0]=wt + (size_t)(18+l)*HH; ma.Wt[1]=wt + (size_t)(21+l)*HH;
    ma.b[0]=mp_bm+(size_t)l*HDIM; ma.b[1]=mp_bp+(size_t)l*HDIM;
    ma.C[0]=nmag; ma.C[1]=nph;
    ma.add = npack;
    k_gemm_mp<<<dim3(1,N_NODES/128,2),512,0,stream>>>(ma);
    if(l < NLAYER-1)
      k_resid_ln<0><<<N_NODES,256,0,stream>>>(nmag, nph, mag, ph, magb, phb, nullptr,
                                              ln_g+(size_t)l*HDIM, ln_b+(size_t)l*HDIM);
    else
      k_resid_ln<1><<<N_NODES,256,0,stream>>>(nmag, nph, mag, ph, magb, phb, tcosb,
                                              ln_g+(size_t)l*HDIM, ln_b+(size_t)l*HDIM);
  }
  k_gemm_proj<<<dim3(1,N_NODES/128),512,0,stream>>>(tcosb, wt + (size_t)24*HH, proj_b, arepr);
  hipMemsetAsync(spool, 0, ((size_t)N_MOLS*HDIM+N_MOLS)*sizeof(float), stream);
  k_pool<<<NH/256,256,0,stream>>>(arepr, node2mol, spool, cntf);
  k_head<<<N_MOLS,256,0,stream>>>(spool, cntf, head_W1, head_b1, head_W2, head_b2, head_W3, head_b3, out);
}

// Round 12
// 857.462 us; speedup vs baseline: 1.0001x; 1.0001x over previous
//
#include <hip/hip_runtime.h>
#include <hip/hip_fp8.h>
#include <math.h>

#define N_NODES 16384
#define N_EDGES 131072
#define N_MOLS 512
#define HDIM 256
#define NLAYER 3
#define NRBF 50
#define CUT 5.0f
#define HH (HDIM*HDIM)

typedef unsigned short u16;
typedef __attribute__((ext_vector_type(8))) short short8v;
typedef __attribute__((ext_vector_type(4))) float f32x4;
typedef __attribute__((ext_vector_type(4))) unsigned short u16x4;
typedef __attribute__((ext_vector_type(8))) unsigned short u16x8;
typedef __attribute__((ext_vector_type(16))) unsigned char u8x16;

__device__ __forceinline__ float softplusf(float x){ return fmaxf(x,0.f)+log1pf(expf(-fabsf(x))); }
__device__ __forceinline__ float siluf(float x){ return x/(1.f+expf(-x)); }
__device__ __forceinline__ float bf2f(u16 u){ union{unsigned int i; float f;}v; v.i=((unsigned int)u)<<16; return v.f; }
__device__ __forceinline__ u16 f2bf(float f){ union{float f; unsigned int i;}v; v.f=f; unsigned int r = v.i + 0x7FFFu + ((v.i>>16)&1u); return (u16)(r>>16); }
__device__ __forceinline__ unsigned char f2e4(float f){
  __hip_fp8_e4m3 t(f); return (unsigned char)t.__x;
}
__device__ __forceinline__ float e42f(unsigned char u){
  __hip_fp8_e4m3 t; t.__x = (__hip_fp8_storage_t)u; return (float)t;
}

__device__ __forceinline__ void gload_lds16(const void* g, void* l){
  __builtin_amdgcn_global_load_lds((const __attribute__((address_space(1))) unsigned int*)g,
                                   (__attribute__((address_space(3))) unsigned int*)l, 16, 0, 0);
}

// ---------------- CSR build ----------------
__global__ void k_hist(const int* __restrict__ dst, int* __restrict__ cnt){
  int e = blockIdx.x*256 + threadIdx.x;
  if(e < N_EDGES) atomicAdd(&cnt[dst[e]], 1);
}

__global__ __launch_bounds__(1024) void k_scan(const int* __restrict__ cnt,
                                               int* __restrict__ rowptr,
                                               int* __restrict__ cursor){
  __shared__ int part[1024];
  int tid = threadIdx.x;
  int base = tid*16;
  int loc[16]; int s=0;
  #pragma unroll
  for(int i=0;i<16;i++){ loc[i]=s; s+=cnt[base+i]; }
  part[tid]=s; __syncthreads();
  for(int off=1; off<1024; off<<=1){
    int v = (tid>=off)? part[tid-off] : 0;
    __syncthreads();
    part[tid] += v;
    __syncthreads();
  }
  int pre = (tid==0)?0:part[tid-1];
  #pragma unroll
  for(int i=0;i<16;i++){ int v = pre+loc[i]; rowptr[base+i]=v; cursor[base+i]=v; }
  if(tid==1023) rowptr[N_NODES]=part[1023];
}

__global__ void k_scatter(const int* __restrict__ dst, const int* __restrict__ src,
                          int* __restrict__ cursor,
                          int* __restrict__ perm, int* __restrict__ srcp){
  int e = blockIdx.x*256+threadIdx.x;
  if(e<N_EDGES){
    int p = atomicAdd(&cursor[dst[e]],1);
    perm[p]=e;
    srcp[p]=src[e];
  }
}

// ---------------- RBF in CSR order (bf16, padded to 64) ----------------
__global__ void k_rbf(const float* __restrict__ dist, const int* __restrict__ perm,
                      u16* __restrict__ rbfp){
  int gid = blockIdx.x*256+threadIdx.x;
  int i = gid>>6, r = gid&63;
  int e = perm[i];
  u16 o = 0;
  if(r<NRBF){
    float d = dist[e];
    float env = 0.5f*(cosf(3.14159265358979f*d/CUT)+1.f) * (d<CUT ? 1.f:0.f);
    float c = CUT*(float)r/(float)(NRBF-1);
    float u = (d - c)/(CUT/(float)NRBF);
    o = f2bf(expf(-0.5f*u*u)*env);
  }
  rbfp[(size_t)i*64+r] = o;
}

// ---------------- weight transpose+convert: W[K][256] f32 -> Wt[256][dK] bf16 ----------------
struct WDesc { const float* src; u16* dst; int K; int dK; };
struct WArgs { WDesc d[28]; };
__global__ __launch_bounds__(256) void k_wconv(WArgs a){
  WDesc w = a.d[blockIdx.x];
  int t = blockIdx.y;
  int ky = t >> 3, nx = t & 7;
  if(ky*32 >= w.dK) return;
  __shared__ float tile[32][33];
  int tid = threadIdx.x;
  int kk = tid >> 3, n4 = (tid & 7)*4;
  int k = ky*32 + kk;
  float4 v = {0.f,0.f,0.f,0.f};
  if(k < w.K) v = *(const float4*)(w.src + (size_t)k*HDIM + nx*32 + n4);
  tile[kk][n4+0]=v.x; tile[kk][n4+1]=v.y; tile[kk][n4+2]=v.z; tile[kk][n4+3]=v.w;
  __syncthreads();
  int nn = tid >> 3, k4 = (tid & 7)*4;
  u16x4 o;
  #pragma unroll
  for(int j=0;j<4;j++) o[j] = f2bf(tile[k4+j][nn]);
  *(u16x4*)(w.dst + (size_t)(nx*32+nn)*w.dK + ky*32 + k4) = o;
}

// ---------------- embedding ----------------
__global__ void k_embed(const float* __restrict__ at, const float* __restrict__ co,
                        const float* __restrict__ Wm, const float* __restrict__ bm,
                        const float* __restrict__ Wp, const float* __restrict__ bp,
                        float* __restrict__ mag, float* __restrict__ ph,
                        u16* __restrict__ magb, u16* __restrict__ phb){
  int n = blockIdx.x; int h = threadIdx.x;
  __shared__ float x[8];
  if(threadIdx.x<5) x[threadIdx.x] = at[n*5+threadIdx.x];
  else if(threadIdx.x<8) x[threadIdx.x] = co[n*3+threadIdx.x-5];
  __syncthreads();
  float tm=bm[h], tp=bp[h];
  #pragma unroll
  for(int i=0;i<8;i++){ tm = fmaf(x[i],Wm[i*HDIM+h],tm); tp = fmaf(x[i],Wp[i*HDIM+h],tp); }
  size_t idx = (size_t)n*HDIM+h;
  float m = softplusf(tm);
  float p = 3.14159265358979f*tanhf(tp);
  mag[idx]=m; ph[idx]=p; magb[idx]=f2bf(m); phb[idx]=f2bf(p);
}

// ======== full-N GEMM core macro: 512 thr, BM=128, BN=256, BK=64 ========
// MODE 3: f32 = x+bias. 4: f32 = x+bias+bf16addend. 7: fp8 = silu(x+bias).
template<int MODE>
__device__ __forceinline__ void gemm_fullN(const u16* __restrict__ A,
                                           const u16* __restrict__ Bt,
                                           const float* __restrict__ bias,
                                           void* __restrict__ outp, int K,
                                           const u16* __restrict__ add=nullptr, int aoff=0){
  __shared__ __align__(16) u16 As[128*64];
  __shared__ __align__(16) u16 Bs[256*64];
  int tid = threadIdx.x;
  int lane = tid & 63, wid = tid >> 6;
  int wm = wid & 1, wn = wid >> 1;
  int m0 = blockIdx.y * 128;
  const size_t Kb = (size_t)K*2;
  f32x4 acc[4][4] = {};
  for(int k0=0;k0<K;k0+=64){
    #pragma unroll
    for(int it=0; it<2; it++){
      int ci = it*512 + tid;
      int row = ci>>3, cl = ci&7;
      int csw = cl ^ (row&7);
      size_t go = (size_t)(m0+row)*Kb + (size_t)k0*2 + csw*16;
      gload_lds16((const char*)A+go, (char*)As + it*8192 + wid*1024);
    }
    #pragma unroll
    for(int it=0; it<4; it++){
      int ci = it*512 + tid;
      int row = ci>>3, cl = ci&7;
      int csw = cl ^ (row&7);
      size_t go = (size_t)row*Kb + (size_t)k0*2 + csw*16;
      gload_lds16((const char*)Bt+go, (char*)Bs + it*8192 + wid*1024);
    }
    __syncthreads();
    #pragma unroll
    for(int ks=0;ks<2;ks++){
      short8v a[4], b[4];
      #pragma unroll
      for(int fm=0;fm<4;fm++){
        int m = wm*64 + fm*16 + (lane&15);
        int ch = (ks*4 + (lane>>4)) ^ (m&7);
        a[fm] = *(const short8v*)&As[m*64 + ch*8];
      }
      #pragma unroll
      for(int fn=0;fn<4;fn++){
        int n = wn*64 + fn*16 + (lane&15);
        int ch = (ks*4 + (lane>>4)) ^ (n&7);
        b[fn] = *(const short8v*)&Bs[n*64 + ch*8];
      }
      #pragma unroll
      for(int fm=0;fm<4;fm++)
        #pragma unroll
        for(int fn=0;fn<4;fn++)
          acc[fm][fn] = __builtin_amdgcn_mfma_f32_16x16x32_bf16(a[fm], b[fn], acc[fm][fn],0,0,0);
    }
    __syncthreads();
  }
  int ro=(lane>>4)*4, co=lane&15;
  #pragma unroll
  for(int fm=0;fm<4;fm++){
    #pragma unroll
    for(int fn=0;fn<4;fn++){
      int col = wn*64 + fn*16 + co;
      float bv = bias ? bias[col] : 0.f;
      #pragma unroll
      for(int r=0;r<4;r++){
        int row = m0 + wm*64 + fm*16 + ro + r;
        float v = acc[fm][fn][r] + bv;
        size_t ci = (size_t)row*256 + col;
        if(MODE==7) ((unsigned char*)outp)[ci] = f2e4(siluf(v));
        else if(MODE==4) ((float*)outp)[ci] = v + bf2f(add[(size_t)row*512 + aoff + col]);
        else ((float*)outp)[ci] = v;
      }
    }
  }
}

__global__ __launch_bounds__(512) void k_gemm_gate(const u16* __restrict__ rbfp,
                                                   const u16* __restrict__ Wt,
                                                   const float* __restrict__ be,
                                                   unsigned char* __restrict__ gate){
  gemm_fullN<7>(rbfp, Wt, be, gate, 64);
}
struct MpArgs { const u16* A[2]; const u16* Wt[2]; const float* b[2]; float* C[2]; const u16* add; };
__global__ __launch_bounds__(512) void k_gemm_mp(MpArgs a){
  int z = blockIdx.z;
  gemm_fullN<4>(a.A[z], a.Wt[z], a.b[z], a.C[z], HDIM, a.add, z==0?0:256);
}
__global__ __launch_bounds__(512) void k_gemm_proj(const u16* __restrict__ Ab,
                                                   const u16* __restrict__ Wt,
                                                   const float* __restrict__ b,
                                                   float* __restrict__ C){
  gemm_fullN<3>(Ab, Wt, b, C, HDIM);
}

// ======== mp GEMM with fused residual (+LayerNorm for z=0) epilogue (layers 0..L-2) ========
// z=0: mag path: v = agg@W + b + npack_m + mag_old; LN over row; -> mag f32 + magb bf16
// z=1: ph  path: v = agg@W + b + npack_p + ph_old;            -> ph  f32 + phb  bf16
struct MpLnArgs { const u16* A[2]; const u16* Wt[2]; const float* b[2]; const u16* add;
                  float* st32[2]; u16* st16[2]; const float* lng; const float* lnb; };
__global__ __launch_bounds__(512) void k_gemm_mp_ln(MpLnArgs a){
  __shared__ __align__(16) u16 As[128*64];
  __shared__ __align__(16) u16 Bs[256*64];
  __shared__ float2 part[4][128];
  int z = blockIdx.z;
  const u16* A = a.A[z];
  const u16* Bt = a.Wt[z];
  const float* bias = a.b[z];
  const u16* add = a.add;
  float* st = a.st32[z];
  u16* stb = a.st16[z];
  int tid = threadIdx.x;
  int lane = tid & 63, wid = tid >> 6;
  int wm = wid & 1, wn = wid >> 1;
  int m0 = blockIdx.y * 128;
  const size_t Kb = 512;
  f32x4 acc[4][4] = {};
  for(int k0=0;k0<256;k0+=64){
    #pragma unroll
    for(int it=0; it<2; it++){
      int ci = it*512 + tid;
      int row = ci>>3, cl = ci&7;
      int csw = cl ^ (row&7);
      size_t go = (size_t)(m0+row)*Kb + (size_t)k0*2 + csw*16;
      gload_lds16((const char*)A+go, (char*)As + it*8192 + wid*1024);
    }
    #pragma unroll
    for(int it=0; it<4; it++){
      int ci = it*512 + tid;
      int row = ci>>3, cl = ci&7;
      int csw = cl ^ (row&7);
      size_t go = (size_t)row*Kb + (size_t)k0*2 + csw*16;
      gload_lds16((const char*)Bt+go, (char*)Bs + it*8192 + wid*1024);
    }
    __syncthreads();
    #pragma unroll
    for(int ks=0;ks<2;ks++){
      short8v av[4], bv[4];
      #pragma unroll
      for(int fm=0;fm<4;fm++){
        int m = wm*64 + fm*16 + (lane&15);
        int ch = (ks*4 + (lane>>4)) ^ (m&7);
        av[fm] = *(const short8v*)&As[m*64 + ch*8];
      }
      #pragma unroll
      for(int fn=0;fn<4;fn++){
        int n = wn*64 + fn*16 + (lane&15);
        int ch = (ks*4 + (lane>>4)) ^ (n&7);
        bv[fn] = *(const short8v*)&Bs[n*64 + ch*8];
      }
      #pragma unroll
      for(int fm=0;fm<4;fm++)
        #pragma unroll
        for(int fn=0;fn<4;fn++)
          acc[fm][fn] = __builtin_amdgcn_mfma_f32_16x16x32_bf16(av[fm], bv[fn], acc[fm][fn],0,0,0);
    }
    __syncthreads();
  }
  int ro=(lane>>4)*4, co=lane&15;
  int aoff = z ? 256 : 0;
  float bcol[4];
  #pragma unroll
  for(int fn=0;fn<4;fn++) bcol[fn] = bias[wn*64+fn*16+co];
  if(z==1){
    #pragma unroll
    for(int fm=0;fm<4;fm++){
      #pragma unroll
      for(int fn=0;fn<4;fn++){
        int col = wn*64+fn*16+co;
        #pragma unroll
        for(int r=0;r<4;r++){
          int row = m0 + wm*64 + fm*16 + ro + r;
          size_t ci = (size_t)row*256 + col;
          float o = acc[fm][fn][r] + bcol[fn] + bf2f(add[(size_t)row*512 + aoff + col]) + st[ci];
          st[ci] = o; stb[ci] = f2bf(o);
        }
      }
    }
    return;
  }
  // z==0: residual + LayerNorm
  float gv[4], bv2[4];
  #pragma unroll
  for(int fn=0;fn<4;fn++){ int col=wn*64+fn*16+co; gv[fn]=a.lng[col]; bv2[fn]=a.lnb[col]; }
  #pragma unroll
  for(int fm=0;fm<4;fm++){
    #pragma unroll
    for(int r=0;r<4;r++){
      int row = m0 + wm*64 + fm*16 + ro + r;
      float s1=0.f, s2=0.f;
      #pragma unroll
      for(int fn=0;fn<4;fn++){
        int col = wn*64+fn*16+co;
        float v = acc[fm][fn][r] + bcol[fn] + bf2f(add[(size_t)row*512 + col]) + st[(size_t)row*256 + col];
        acc[fm][fn][r] = v;
        s1 += v; s2 += v*v;
      }
      #pragma unroll
      for(int off=8; off; off>>=1){ s1 += __shfl_xor(s1,off,64); s2 += __shfl_xor(s2,off,64); }
      if(co==0){ float2 p; p.x=s1; p.y=s2; part[wn][wm*64+fm*16+ro+r] = p; }
    }
  }
  __syncthreads();
  #pragma unroll
  for(int fm=0;fm<4;fm++){
    #pragma unroll
    for(int r=0;r<4;r++){
      int rl = wm*64+fm*16+ro+r;
      float2 p0=part[0][rl], p1=part[1][rl], p2=part[2][rl], p3=part[3][rl];
      float s1 = p0.x+p1.x+p2.x+p3.x;
      float s2 = p0.y+p1.y+p2.y+p3.y;
      float mu = s1*(1.f/256.f);
      float var = s2*(1.f/256.f) - mu*mu;
      float rs = rsqrtf(var + 1e-5f);
      int row = m0 + rl;
      #pragma unroll
      for(int fn=0;fn<4;fn++){
        int col = wn*64+fn*16+co;
        size_t ci = (size_t)row*256 + col;
        float o = (acc[fm][fn][r]-mu)*rs*gv[fn] + bv2[fn];
        st[ci] = o; stb[ci] = f2bf(o);
      }
    }
  }
}

// ======== full-N PAIR GEMM for QKV (mag & ph together) + sincos epilogue ========
struct Qkv3Args { const u16* Wm[3]; const u16* Wp[3]; u16* qpk; u16* kvpk; };
__global__ __launch_bounds__(512) void k_gemm_qkv3(const u16* __restrict__ magb,
                                                   const u16* __restrict__ phb,
                                                   Qkv3Args a){
  __shared__ __align__(16) u16 Ams[128*64];
  __shared__ __align__(16) u16 Aps[128*64];
  __shared__ __align__(16) u16 Bms[256*64];
  __shared__ __align__(16) u16 Bps[256*64];
  int z = blockIdx.z;
  const u16* Wmz = a.Wm[z];
  const u16* Wpz = a.Wp[z];
  int tid = threadIdx.x;
  int lane = tid & 63, wid = tid >> 6;
  int wm = wid & 1, wn = wid >> 1;
  int m0 = blockIdx.y * 128;
  const size_t Kb = 512;  // K=256 bf16
  f32x4 accm[4][4] = {}, accp[4][4] = {};
  for(int k0=0;k0<256;k0+=64){
    #pragma unroll
    for(int it=0; it<2; it++){
      int ci = it*512 + tid;
      int row = ci>>3, cl = ci&7;
      int csw = cl ^ (row&7);
      size_t go = (size_t)(m0+row)*Kb + (size_t)k0*2 + csw*16;
      gload_lds16((const char*)magb+go, (char*)Ams + it*8192 + wid*1024);
      gload_lds16((const char*)phb +go, (char*)Aps + it*8192 + wid*1024);
    }
    #pragma unroll
    for(int it=0; it<4; it++){
      int ci = it*512 + tid;
      int row = ci>>3, cl = ci&7;
      int csw = cl ^ (row&7);
      size_t go = (size_t)row*Kb + (size_t)k0*2 + csw*16;
      gload_lds16((const char*)Wmz+go, (char*)Bms + it*8192 + wid*1024);
      gload_lds16((const char*)Wpz+go, (char*)Bps + it*8192 + wid*1024);
    }
    __syncthreads();
    #pragma unroll
    for(int ks=0;ks<2;ks++){
      short8v am[4], ap[4], bm_[4], bp_[4];
      #pragma unroll
      for(int fm=0;fm<4;fm++){
        int m = wm*64 + fm*16 + (lane&15);
        int ch = (ks*4 + (lane>>4)) ^ (m&7);
        am[fm] = *(const short8v*)&Ams[m*64 + ch*8];
        ap[fm] = *(const short8v*)&Aps[m*64 + ch*8];
      }
      #pragma unroll
      for(int fn=0;fn<4;fn++){
        int n = wn*64 + fn*16 + (lane&15);
        int ch = (ks*4 + (lane>>4)) ^ (n&7);
        bm_[fn] = *(const short8v*)&Bms[n*64 + ch*8];
        bp_[fn] = *(const short8v*)&Bps[n*64 + ch*8];
      }
      #pragma unroll
      for(int fm=0;fm<4;fm++)
        #pragma unroll
        for(int fn=0;fn<4;fn++){
          accm[fm][fn] = __builtin_amdgcn_mfma_f32_16x16x32_bf16(am[fm], bm_[fn], accm[fm][fn],0,0,0);
          accp[fm][fn] = __builtin_amdgcn_mfma_f32_16x16x32_bf16(ap[fm], bp_[fn], accp[fm][fn],0,0,0);
        }
    }
    __syncthreads();
  }
  int ro=(lane>>4)*4, co=lane&15;
  #pragma unroll
  for(int fm=0;fm<4;fm++){
    #pragma unroll
    for(int fn=0;fn<4;fn++){
      int col = wn*64 + fn*16 + co;
      #pragma unroll
      for(int r=0;r<4;r++){
        int row = m0 + wm*64 + fm*16 + ro + r;
        float mv = accm[fm][fn][r];
        float pv = accp[fm][fn][r];
        u16 o0, o1;
        if(z<2){
          float sn, cs;
          __sincosf(pv, &sn, &cs);
          o0 = f2bf(mv*cs); o1 = f2bf(mv*sn);
        } else {
          o0 = f2bf(mv); o1 = f2bf(pv);
        }
        u16* base = (z==0) ? (a.qpk + (size_t)row*512)
                           : (a.kvpk + (size_t)row*1024 + (z==2 ? 512 : 0));
        base[col] = o0;
        base[col+256] = o1;
      }
    }
  }
}

// ---------------- fused attention v4: 4 edge-streams/wave, 16 lanes x 16 ch ----------------
__global__ __launch_bounds__(256) void k_attn_fused(
    const int* __restrict__ rowptr, const int* __restrict__ srcp,
    const u16* __restrict__ qpack, const u16* __restrict__ kvpack,
    const u16* __restrict__ rbfp,
    const float* __restrict__ We, const float* __restrict__ be,
    u16* __restrict__ npack)
{
  int wid = threadIdx.x >> 6, lane = threadIdx.x & 63;
  int gid = lane >> 4, l = lane & 15;
  int d = blockIdx.x*4 + wid;
  int b = rowptr[d], e = rowptr[d+1];
  const u16* qb = qpack + (size_t)d*512 + l*16;
  u16x8 qc0 = *(const u16x8*)qb;
  u16x8 qc1 = *(const u16x8*)(qb+8);
  u16x8 qs0 = *(const u16x8*)(qb+256);
  u16x8 qs1 = *(const u16x8*)(qb+264);
  float qcf[16], qsf[16];
  #pragma unroll
  for(int j=0;j<8;j++){
    qcf[j]=bf2f(qc0[j]); qcf[j+8]=bf2f(qc1[j]);
    qsf[j]=bf2f(qs0[j]); qsf[j+8]=bf2f(qs1[j]);
  }
  float Wef[4];
  #pragma unroll
  for(int k=0;k<4;k++) Wef[k] = (l*4+k < NRBF) ? We[l*4+k] : 0.f;
  float be0 = be[0];
  float z = 0.f;
  float avm[16], avp[16];
  #pragma unroll
  for(int j=0;j<16;j++){ avm[j]=0.f; avp[j]=0.f; }
  for(int i = b + gid; i < e; i += 4){
    int s = srcp[i];
    const u16* kb = kvpack + (size_t)s*1024 + l*16;
    u16x8 kc0 = *(const u16x8*)kb;
    u16x8 kc1 = *(const u16x8*)(kb+8);
    u16x8 ks0 = *(const u16x8*)(kb+256);
    u16x8 ks1 = *(const u16x8*)(kb+264);
    u16x8 vm0 = *(const u16x8*)(kb+512);
    u16x8 vm1 = *(const u16x8*)(kb+520);
    u16x8 vp0 = *(const u16x8*)(kb+768);
    u16x8 vp1 = *(const u16x8*)(kb+776);
    u16x4 rb4 = *(const u16x4*)(rbfp + (size_t)i*64 + l*4);
    float p = 0.f;
    #pragma unroll
    for(int j=0;j<8;j++){
      p = fmaf(qcf[j],   bf2f(kc0[j]), p);
      p = fmaf(qcf[j+8], bf2f(kc1[j]), p);
      p = fmaf(qsf[j],   bf2f(ks0[j]), p);
      p = fmaf(qsf[j+8], bf2f(ks1[j]), p);
    }
    float t = p*0.0625f;
    #pragma unroll
    for(int k=0;k<4;k++) t = fmaf(bf2f(rb4[k]), Wef[k], t);
    #pragma unroll
    for(int off=8; off; off>>=1) t += __shfl_xor(t, off, 64);
    float w = __expf(t + be0);   // scores O(1): softmax shift-invariant
    z += w;
    #pragma unroll
    for(int j=0;j<8;j++){
      avm[j]   = fmaf(w, bf2f(vm0[j]), avm[j]);
      avm[j+8] = fmaf(w, bf2f(vm1[j]), avm[j+8]);
      avp[j]   = fmaf(w, bf2f(vp0[j]), avp[j]);
      avp[j+8] = fmaf(w, bf2f(vp1[j]), avp[j+8]);
    }
  }
  z += __shfl_xor(z, 16, 64);
  z += __shfl_xor(z, 32, 64);
  #pragma unroll
  for(int j=0;j<16;j++){
    avm[j] += __shfl_xor(avm[j], 16, 64);
    avm[j] += __shfl_xor(avm[j], 32, 64);
    avp[j] += __shfl_xor(avp[j], 16, 64);
    avp[j] += __shfl_xor(avp[j], 32, 64);
  }
  if(gid==0){
    float inv = 1.f/(z + 1e-9f);
    u16x8 m0, m1, p0, p1;
    #pragma unroll
    for(int j=0;j<8;j++){
      m0[j]=f2bf(avm[j]*inv); m1[j]=f2bf(avm[j+8]*inv);
      p0[j]=f2bf(avp[j]*inv); p1[j]=f2bf(avp[j+8]*inv);
    }
    u16* nb = npack + (size_t)d*512 + l*16;
    *(u16x8*)nb = m0;       *(u16x8*)(nb+8)   = m1;
    *(u16x8*)(nb+256) = p0; *(u16x8*)(nb+264) = p1;
  }
}

// ---------------- message passing aggregation v5 (fp8 gate, 4 streams) ----------------
__global__ __launch_bounds__(256) void k_mp_agg(const int* __restrict__ rowptr,
                         const int* __restrict__ srcp, const unsigned char* __restrict__ gate,
                         const u16* __restrict__ npack,
                         u16* __restrict__ aggm, u16* __restrict__ aggp){
  int wid = threadIdx.x >> 6, lane = threadIdx.x & 63;
  int gid = lane >> 4, l = lane & 15;
  int n = blockIdx.x*4 + wid;
  int b = rowptr[n], e = rowptr[n+1];
  float am[16], ap[16];
  #pragma unroll
  for(int j=0;j<16;j++){ am[j]=0.f; ap[j]=0.f; }
  for(int i = b + gid; i < e; i += 4){
    int s = srcp[i];
    u8x16 g16 = *(const u8x16*)(gate + (size_t)i*256 + l*16);
    const u16* nb = npack + (size_t)s*512 + l*16;
    u16x8 m0 = *(const u16x8*)nb;
    u16x8 m1 = *(const u16x8*)(nb+8);
    u16x8 p0 = *(const u16x8*)(nb+256);
    u16x8 p1 = *(const u16x8*)(nb+264);
    #pragma unroll
    for(int j=0;j<8;j++){
      float ga = e42f(g16[j]), gb2 = e42f(g16[j+8]);
      am[j]   = fmaf(ga,  bf2f(m0[j]), am[j]);
      am[j+8] = fmaf(gb2, bf2f(m1[j]), am[j+8]);
      ap[j]   = fmaf(ga,  bf2f(p0[j]), ap[j]);
      ap[j+8] = fmaf(gb2, bf2f(p1[j]), ap[j+8]);
    }
  }
  #pragma unroll
  for(int j=0;j<16;j++){
    am[j] += __shfl_xor(am[j], 16, 64);
    am[j] += __shfl_xor(am[j], 32, 64);
    ap[j] += __shfl_xor(ap[j], 16, 64);
    ap[j] += __shfl_xor(ap[j], 32, 64);
  }
  if(gid==0){
    u16x8 a0, a1, b0, b1;
    #pragma unroll
    for(int j=0;j<8;j++){
      a0[j]=f2bf(am[j]); a1[j]=f2bf(am[j+8]);
      b0[j]=f2bf(ap[j]); b1[j]=f2bf(ap[j+8]);
    }
    size_t o = (size_t)n*256 + l*16;
    *(u16x8*)(aggm + o) = a0; *(u16x8*)(aggm + o + 8) = a1;
    *(u16x8*)(aggp + o) = b0; *(u16x8*)(aggp + o + 8) = b1;
  }
}

// ---------------- residual + LayerNorm, last layer (fuses mag*cos(ph) projection input) ----
__global__ __launch_bounds__(256) void k_resid_ln_last(const float* __restrict__ nmag, const float* __restrict__ nph,
                           const float* __restrict__ mag, const float* __restrict__ ph,
                           u16* __restrict__ tcosb,
                           const float* __restrict__ g, const float* __restrict__ b){
  int n = blockIdx.x, tid = threadIdx.x;
  size_t idx = (size_t)n*HDIM+tid;
  float t = nmag[idx] + mag[idx];
  float s1=t, s2=t*t;
  #pragma unroll
  for(int off=32; off; off>>=1){ s1 += __shfl_down(s1,off,64); s2 += __shfl_down(s2,off,64); }
  __shared__ float w1[4], w2[4], bc[2];
  int wid = tid>>6, lane = tid&63;
  if(lane==0){ w1[wid]=s1; w2[wid]=s2; }
  __syncthreads();
  if(tid==0){
    float a=w1[0]+w1[1]+w1[2]+w1[3];
    float q=w2[0]+w2[1]+w2[2]+w2[3];
    float mu = a*(1.f/HDIM);
    float var = q*(1.f/HDIM) - mu*mu;
    bc[0]=mu; bc[1]=rsqrtf(var+1e-5f);
  }
  __syncthreads();
  float mu=bc[0], rs=bc[1];
  float ln = (t-mu)*rs*g[tid]+b[tid];
  float p2 = nph[idx] + ph[idx];
  tcosb[idx] = f2bf(ln*__cosf(p2));
}

// ---------------- pooling ----------------
__global__ void k_pool(const float* __restrict__ arepr, const int* __restrict__ n2m,
                       float* __restrict__ spool, float* __restrict__ cntf){
  int gid = blockIdx.x*256+threadIdx.x;
  int n = gid>>8, h = gid&255;
  int m = n2m[n];
  atomicAdd(&spool[(size_t)m*HDIM+h], arepr[(size_t)n*HDIM+h]);
  if(h==0) atomicAdd(&cntf[m], 1.f);
}

// ---------------- head MLP ----------------
__global__ __launch_bounds__(256) void k_head(const float* __restrict__ spool, const float* __restrict__ cntf,
                       const float* __restrict__ W1, const float* __restrict__ b1,
                       const float* __restrict__ W2, const float* __restrict__ b2,
                       const float* __restrict__ W3, const float* __restrict__ b3,
                       float* __restrict__ out){
  __shared__ float smol[2*HDIM];
  __shared__ float sh1[HDIM];
  __shared__ float sh2[HDIM/2];
  int m = blockIdx.x, tid = threadIdx.x;
  float sv = spool[(size_t)m*HDIM+tid];
  float c = cntf[m];
  smol[tid] = sv/fmaxf(c,1.f);
  smol[HDIM+tid] = sv;
  __syncthreads();
  float a = b1[tid];
  for(int i=0;i<2*HDIM;i++) a = fmaf(smol[i], W1[i*HDIM+tid], a);
  sh1[tid] = siluf(a);
  __syncthreads();
  if(tid<128){
    float a2 = b2[tid];
    for(int i=0;i<HDIM;i++) a2 = fmaf(sh1[i], W2[i*128+tid], a2);
    sh2[tid] = siluf(a2);
  }
  __syncthreads();
  if(tid<64){
    float p = sh2[tid]*W3[tid] + sh2[tid+64]*W3[tid+64];
    #pragma unroll
    for(int off=32; off; off>>=1) p += __shfl_down(p,off,64);
    if(tid==0) out[m] = p + b3[0];
  }
}

extern "C" void kernel_launch(void* const* d_in, const int* in_sizes, int n_in,
                              void* d_out, int out_size, void* d_ws, size_t ws_size,
                              hipStream_t stream){
  const float* atom_types = (const float*)d_in[0];
  const float* coords     = (const float*)d_in[1];
  const float* edge_dist  = (const float*)d_in[2];
  const int*   edge_index = (const int*)d_in[3];
  const int*   node2mol   = (const int*)d_in[4];
  const float* emb_Wm = (const float*)d_in[5];
  const float* emb_bm = (const float*)d_in[6];
  const float* emb_Wp = (const float*)d_in[7];
  const float* emb_bp = (const float*)d_in[8];
  const float* attn_Wqm = (const float*)d_in[9];
  const float* attn_Wkm = (const float*)d_in[10];
  const float* attn_Wvm = (const float*)d_in[11];
  const float* attn_Wqp = (const float*)d_in[12];
  const float* attn_Wkp = (const float*)d_in[13];
  const float* attn_Wvp = (const float*)d_in[14];
  const float* attn_We  = (const float*)d_in[15];
  const float* attn_be  = (const float*)d_in[16];
  const float* mp_We = (const float*)d_in[17];
  const float* mp_be = (const float*)d_in[18];
  const float* mp_Wm = (const float*)d_in[19];
  const float* mp_bm = (const float*)d_in[20];
  const float* mp_Wp = (const float*)d_in[21];
  const float* mp_bp = (const float*)d_in[22];
  const float* ln_g = (const float*)d_in[23];
  const float* ln_b = (const float*)d_in[24];
  const float* proj_W = (const float*)d_in[25];
  const float* proj_b = (const float*)d_in[26];
  const float* head_W1 = (const float*)d_in[27];
  const float* head_b1 = (const float*)d_in[28];
  const float* head_W2 = (const float*)d_in[29];
  const float* head_b2 = (const float*)d_in[30];
  const float* head_W3 = (const float*)d_in[31];
  const float* head_b3 = (const float*)d_in[32];
  float* out = (float*)d_out;

  float* ws = (float*)d_ws;
  const size_t NH = (size_t)N_NODES*HDIM;
  size_t o = 0;
  float* mag = ws + o; o += NH;
  float* ph  = ws + o; o += NH;
  float* nmag= ws + o; o += NH;
  float* nph = ws + o; o += NH;
  float* spool = ws + o; o += (size_t)N_MOLS*HDIM;
  float* cntf  = ws + o; o += N_MOLS;
  int* rowptr = (int*)(ws + o); o += N_NODES+1;
  int* cnt    = (int*)(ws + o); o += N_NODES;
  int* cursor = (int*)(ws + o); o += N_NODES;
  int* perm   = (int*)(ws + o); o += N_EDGES;
  int* srcp   = (int*)(ws + o); o += N_EDGES + 1;   // +1 keeps 8B alignment after
  u16* magb = (u16*)(ws + o); o += NH/2;
  u16* phb  = (u16*)(ws + o); o += NH/2;
  u16* aggmb= (u16*)(ws + o); o += NH/2;
  u16* aggpb= (u16*)(ws + o); o += NH/2;
  u16* npack= (u16*)(ws + o); o += NH;                        // [N][512] bf16 (mag|ph)
  u16* rbfp = (u16*)(ws + o); o += (size_t)N_EDGES*32;        // [E][64] bf16, CSR order
  u16* qpack= (u16*)(ws + o); o += NH;                        // [N][512] bf16 (qc|qs)
  u16* kvpack=(u16*)(ws + o); o += 2*NH;                      // [N][1024] bf16 (kc|ks|vm|vp)
  o += NH;                                                    // pad: gatep tail
  u16* wt   = (u16*)(ws + o); o += (25*(size_t)HH + 3*HDIM*64)/2;
  unsigned char* gatep = (unsigned char*)qpack;  // [E][256] fp8 CSR order (disjoint lifetime)
  float* arepr = nmag;     // free after last resid_ln
  u16* tcosb = aggmb;      // free after last mp gemm

  const int* src = edge_index;
  const int* dst = edge_index + N_EDGES;

  // ---- weight convert/transpose descriptors ----
  WArgs wa;
  for(int l=0;l<NLAYER;l++){
    const float* srcs[6] = {attn_Wqm+(size_t)l*HH, attn_Wkm+(size_t)l*HH, attn_Wvm+(size_t)l*HH,
                            attn_Wqp+(size_t)l*HH, attn_Wkp+(size_t)l*HH, attn_Wvp+(size_t)l*HH};
    for(int j=0;j<6;j++){ wa.d[l*6+j] = { srcs[j], wt + (size_t)(l*6+j)*HH, HDIM, HDIM }; }
    wa.d[18+l] = { mp_Wm+(size_t)l*HH, wt + (size_t)(18+l)*HH, HDIM, HDIM };
    wa.d[21+l] = { mp_Wp+(size_t)l*HH, wt + (size_t)(21+l)*HH, HDIM, HDIM };
    wa.d[25+l] = { mp_We+(size_t)l*NRBF*HDIM, wt + (size_t)25*HH + (size_t)l*HDIM*64, NRBF, 64 };
  }
  wa.d[24] = { proj_W, wt + (size_t)24*HH, HDIM, HDIM };

  hipMemsetAsync(cnt, 0, N_NODES*sizeof(int), stream);
  k_hist<<<N_EDGES/256,256,0,stream>>>(dst, cnt);
  k_scan<<<1,1024,0,stream>>>(cnt, rowptr, cursor);
  k_scatter<<<N_EDGES/256,256,0,stream>>>(dst, src, cursor, perm, srcp);
  k_wconv<<<dim3(28,64),256,0,stream>>>(wa);
  k_rbf<<<(N_EDGES*64)/256,256,0,stream>>>(edge_dist, perm, rbfp);
  k_embed<<<N_NODES,256,0,stream>>>(atom_types, coords, emb_Wm, emb_bm, emb_Wp, emb_bp,
                                    mag, ph, magb, phb);

  for(int l=0;l<NLAYER;l++){
    Qkv3Args qa;
    qa.Wm[0] = wt + (size_t)(l*6+0)*HH;  // Wqm
    qa.Wm[1] = wt + (size_t)(l*6+1)*HH;  // Wkm
    qa.Wm[2] = wt + (size_t)(l*6+2)*HH;  // Wvm
    qa.Wp[0] = wt + (size_t)(l*6+3)*HH;  // Wqp
    qa.Wp[1] = wt + (size_t)(l*6+4)*HH;  // Wkp
    qa.Wp[2] = wt + (size_t)(l*6+5)*HH;  // Wvp
    qa.qpk = qpack; qa.kvpk = kvpack;
    k_gemm_qkv3<<<dim3(1,N_NODES/128,3),512,0,stream>>>(magb, phb, qa);
    k_attn_fused<<<N_NODES/4,256,0,stream>>>(rowptr, srcp, qpack, kvpack,
                                             rbfp, attn_We+(size_t)l*NRBF, attn_be+l,
                                             npack);
    k_gemm_gate<<<dim3(1,N_EDGES/128),512,0,stream>>>(rbfp, wt + (size_t)25*HH + (size_t)l*HDIM*64,
                                                      mp_be+(size_t)l*HDIM, gatep);
    k_mp_agg<<<N_NODES/4,256,0,stream>>>(rowptr, srcp, gatep, npack, aggmb, aggpb);
    if(l < NLAYER-1){
      MpLnArgs ml;
      ml.A[0]=aggmb; ml.A[1]=aggpb;
      ml.Wt[0]=wt + (size_t)(18+l)*HH; ml.Wt[1]=wt + (size_t)(21+l)*HH;
      ml.b[0]=mp_bm+(size_t)l*HDIM; ml.b[1]=mp_bp+(size_t)l*HDIM;
      ml.add = npack;
      ml.st32[0]=mag; ml.st32[1]=ph; ml.st16[0]=magb; ml.st16[1]=phb;
      ml.lng = ln_g+(size_t)l*HDIM; ml.lnb = ln_b+(size_t)l*HDIM;
      k_gemm_mp_ln<<<dim3(1,N_NODES/128,2),512,0,stream>>>(ml);
    } else {
      MpArgs ma;
      ma.A[0]=aggmb; ma.A[1]=aggpb;
      ma.Wt[0]=wt + (size_t)(18+l)*HH; ma.Wt[1]=wt + (size_t)(21+l)*HH;
      ma.b[0]=mp_bm+(size_t)l*HDIM; ma.b[1]=mp_bp+(size_t)l*HDIM;
      ma.C[0]=nmag; ma.C[1]=nph;
      ma.add = npack;
      k_gemm_mp<<<dim3(1,N_NODES/128,2),512,0,stream>>>(ma);
      k_resid_ln_last<<<N_NODES,256,0,stream>>>(nmag, nph, mag, ph, tcosb,
                                                ln_g+(size_t)l*HDIM, ln_b+(size_t)l*HDIM);
    }
  }
  k_gemm_proj<<<dim3(1,N_NODES/128),512,0,stream>>>(tcosb, wt + (size_t)24*HH, proj_b, arepr);
  hipMemsetAsync(spool, 0, ((size_t)N_MOLS*HDIM+N_MOLS)*sizeof(float), stream);
  k_pool<<<NH/256,256,0,stream>>>(arepr, node2mol, spool, cntf);
  k_head<<<N_MOLS,256,0,stream>>>(spool, cntf, head_W1, head_b1, head_W2, head_b2, head_W3, head_b3, out);
}

// Round 13
// 818.613 us; speedup vs baseline: 1.0476x; 1.0475x over previous
//
#include <hip/hip_runtime.h>
#include <math.h>

#define N_NODES 16384
#define N_EDGES 131072
#define N_MOLS 512
#define HDIM 256
#define NLAYER 3
#define NRBF 50
#define CUT 5.0f
#define HH (HDIM*HDIM)

typedef unsigned short u16;
typedef __attribute__((ext_vector_type(8))) short short8v;
typedef __attribute__((ext_vector_type(4))) float f32x4;
typedef __attribute__((ext_vector_type(4))) unsigned short u16x4;
typedef __attribute__((ext_vector_type(8))) unsigned short u16x8;
typedef __attribute__((ext_vector_type(16))) unsigned char u8x16;

__device__ __forceinline__ float softplusf(float x){ return fmaxf(x,0.f)+log1pf(expf(-fabsf(x))); }
__device__ __forceinline__ float siluf(float x){ return x/(1.f+expf(-x)); }
__device__ __forceinline__ float fsiluf(float x){ return x/(1.f+__expf(-x)); }
__device__ __forceinline__ float bf2f(u16 u){ union{unsigned int i; float f;}v; v.i=((unsigned int)u)<<16; return v.f; }
__device__ __forceinline__ u16 f2bf(float f){ union{float f; unsigned int i;}v; v.f=f; unsigned int r = v.i + 0x7FFFu + ((v.i>>16)&1u); return (u16)(r>>16); }
// gfx950 OCP fp8 e4m3: hardware convert instructions
__device__ __forceinline__ unsigned char f2e4(float f){
  return (unsigned char)(__builtin_amdgcn_cvt_pk_fp8_f32(f, f, 0, false) & 0xFF);
}
__device__ __forceinline__ float e42f(unsigned char u){
  return __builtin_amdgcn_cvt_f32_fp8((int)u, 0);
}

__device__ __forceinline__ void gload_lds16(const void* g, void* l){
  __builtin_amdgcn_global_load_lds((const __attribute__((address_space(1))) unsigned int*)g,
                                   (__attribute__((address_space(3))) unsigned int*)l, 16, 0, 0);
}

// ---------------- CSR build ----------------
__global__ void k_hist(const int* __restrict__ dst, int* __restrict__ cnt){
  int e = blockIdx.x*256 + threadIdx.x;
  if(e < N_EDGES) atomicAdd(&cnt[dst[e]], 1);
}

__global__ __launch_bounds__(1024) void k_scan(const int* __restrict__ cnt,
                                               int* __restrict__ rowptr,
                                               int* __restrict__ cursor){
  __shared__ int part[1024];
  int tid = threadIdx.x;
  int base = tid*16;
  int loc[16]; int s=0;
  #pragma unroll
  for(int i=0;i<16;i++){ loc[i]=s; s+=cnt[base+i]; }
  part[tid]=s; __syncthreads();
  for(int off=1; off<1024; off<<=1){
    int v = (tid>=off)? part[tid-off] : 0;
    __syncthreads();
    part[tid] += v;
    __syncthreads();
  }
  int pre = (tid==0)?0:part[tid-1];
  #pragma unroll
  for(int i=0;i<16;i++){ int v = pre+loc[i]; rowptr[base+i]=v; cursor[base+i]=v; }
  if(tid==1023) rowptr[N_NODES]=part[1023];
}

__global__ void k_scatter(const int* __restrict__ dst, const int* __restrict__ src,
                          int* __restrict__ cursor,
                          int* __restrict__ perm, int* __restrict__ srcp){
  int e = blockIdx.x*256+threadIdx.x;
  if(e<N_EDGES){
    int p = atomicAdd(&cursor[dst[e]],1);
    perm[p]=e;
    srcp[p]=src[e];
  }
}

// ---------------- RBF in CSR order (bf16, padded to 64) ----------------
__global__ void k_rbf(const float* __restrict__ dist, const int* __restrict__ perm,
                      u16* __restrict__ rbfp){
  int gid = blockIdx.x*256+threadIdx.x;
  int i = gid>>6, r = gid&63;
  int e = perm[i];
  u16 o = 0;
  if(r<NRBF){
    float d = dist[e];
    float env = 0.5f*(cosf(3.14159265358979f*d/CUT)+1.f) * (d<CUT ? 1.f:0.f);
    float c = CUT*(float)r/(float)(NRBF-1);
    float u = (d - c)/(CUT/(float)NRBF);
    o = f2bf(expf(-0.5f*u*u)*env);
  }
  rbfp[(size_t)i*64+r] = o;
}

// ---------------- weight transpose+convert: W[K][256] f32 -> Wt[256][dK] bf16 ----------------
struct WDesc { const float* src; u16* dst; int K; int dK; };
struct WArgs { WDesc d[28]; };
__global__ __launch_bounds__(256) void k_wconv(WArgs a){
  WDesc w = a.d[blockIdx.x];
  int t = blockIdx.y;
  int ky = t >> 3, nx = t & 7;
  if(ky*32 >= w.dK) return;
  __shared__ float tile[32][33];
  int tid = threadIdx.x;
  int kk = tid >> 3, n4 = (tid & 7)*4;
  int k = ky*32 + kk;
  float4 v = {0.f,0.f,0.f,0.f};
  if(k < w.K) v = *(const float4*)(w.src + (size_t)k*HDIM + nx*32 + n4);
  tile[kk][n4+0]=v.x; tile[kk][n4+1]=v.y; tile[kk][n4+2]=v.z; tile[kk][n4+3]=v.w;
  __syncthreads();
  int nn = tid >> 3, k4 = (tid & 7)*4;
  u16x4 o;
  #pragma unroll
  for(int j=0;j<4;j++) o[j] = f2bf(tile[k4+j][nn]);
  *(u16x4*)(w.dst + (size_t)(nx*32+nn)*w.dK + ky*32 + k4) = o;
}

// ---------------- embedding ----------------
__global__ void k_embed(const float* __restrict__ at, const float* __restrict__ co,
                        const float* __restrict__ Wm, const float* __restrict__ bm,
                        const float* __restrict__ Wp, const float* __restrict__ bp,
                        float* __restrict__ mag, float* __restrict__ ph,
                        u16* __restrict__ magb, u16* __restrict__ phb){
  int n = blockIdx.x; int h = threadIdx.x;
  __shared__ float x[8];
  if(threadIdx.x<5) x[threadIdx.x] = at[n*5+threadIdx.x];
  else if(threadIdx.x<8) x[threadIdx.x] = co[n*3+threadIdx.x-5];
  __syncthreads();
  float tm=bm[h], tp=bp[h];
  #pragma unroll
  for(int i=0;i<8;i++){ tm = fmaf(x[i],Wm[i*HDIM+h],tm); tp = fmaf(x[i],Wp[i*HDIM+h],tp); }
  size_t idx = (size_t)n*HDIM+h;
  float m = softplusf(tm);
  float p = 3.14159265358979f*tanhf(tp);
  mag[idx]=m; ph[idx]=p; magb[idx]=f2bf(m); phb[idx]=f2bf(p);
}

// ======== full-N GEMM core macro: 512 thr, BM=128, BN=256, BK=64 ========
// MODE 3: f32 = x+bias. 4: f32 = x+bias+bf16addend. 7: fp8 = silu(x+bias).
template<int MODE>
__device__ __forceinline__ void gemm_fullN(const u16* __restrict__ A,
                                           const u16* __restrict__ Bt,
                                           const float* __restrict__ bias,
                                           void* __restrict__ outp, int K,
                                           const u16* __restrict__ add=nullptr, int aoff=0){
  __shared__ __align__(16) u16 As[128*64];
  __shared__ __align__(16) u16 Bs[256*64];
  int tid = threadIdx.x;
  int lane = tid & 63, wid = tid >> 6;
  int wm = wid & 1, wn = wid >> 1;
  int m0 = blockIdx.y * 128;
  const size_t Kb = (size_t)K*2;
  f32x4 acc[4][4] = {};
  for(int k0=0;k0<K;k0+=64){
    #pragma unroll
    for(int it=0; it<2; it++){
      int ci = it*512 + tid;
      int row = ci>>3, cl = ci&7;
      int csw = cl ^ (row&7);
      size_t go = (size_t)(m0+row)*Kb + (size_t)k0*2 + csw*16;
      gload_lds16((const char*)A+go, (char*)As + it*8192 + wid*1024);
    }
    #pragma unroll
    for(int it=0; it<4; it++){
      int ci = it*512 + tid;
      int row = ci>>3, cl = ci&7;
      int csw = cl ^ (row&7);
      size_t go = (size_t)row*Kb + (size_t)k0*2 + csw*16;
      gload_lds16((const char*)Bt+go, (char*)Bs + it*8192 + wid*1024);
    }
    __syncthreads();
    #pragma unroll
    for(int ks=0;ks<2;ks++){
      short8v a[4], b[4];
      #pragma unroll
      for(int fm=0;fm<4;fm++){
        int m = wm*64 + fm*16 + (lane&15);
        int ch = (ks*4 + (lane>>4)) ^ (m&7);
        a[fm] = *(const short8v*)&As[m*64 + ch*8];
      }
      #pragma unroll
      for(int fn=0;fn<4;fn++){
        int n = wn*64 + fn*16 + (lane&15);
        int ch = (ks*4 + (lane>>4)) ^ (n&7);
        b[fn] = *(const short8v*)&Bs[n*64 + ch*8];
      }
      #pragma unroll
      for(int fm=0;fm<4;fm++)
        #pragma unroll
        for(int fn=0;fn<4;fn++)
          acc[fm][fn] = __builtin_amdgcn_mfma_f32_16x16x32_bf16(a[fm], b[fn], acc[fm][fn],0,0,0);
    }
    __syncthreads();
  }
  int ro=(lane>>4)*4, co=lane&15;
  #pragma unroll
  for(int fm=0;fm<4;fm++){
    #pragma unroll
    for(int fn=0;fn<4;fn++){
      int col = wn*64 + fn*16 + co;
      float bv = bias ? bias[col] : 0.f;
      #pragma unroll
      for(int r=0;r<4;r++){
        int row = m0 + wm*64 + fm*16 + ro + r;
        float v = acc[fm][fn][r] + bv;
        size_t ci = (size_t)row*256 + col;
        if(MODE==7) ((unsigned char*)outp)[ci] = f2e4(fsiluf(v));
        else if(MODE==4) ((float*)outp)[ci] = v + bf2f(add[(size_t)row*512 + aoff + col]);
        else ((float*)outp)[ci] = v;
      }
    }
  }
}

__global__ __launch_bounds__(512) void k_gemm_gate(const u16* __restrict__ rbfp,
                                                   const u16* __restrict__ Wt,
                                                   const float* __restrict__ be,
                                                   unsigned char* __restrict__ gate){
  gemm_fullN<7>(rbfp, Wt, be, gate, 64);
}
struct MpArgs { const u16* A[2]; const u16* Wt[2]; const float* b[2]; float* C[2]; const u16* add; };
__global__ __launch_bounds__(512) void k_gemm_mp(MpArgs a){
  int z = blockIdx.z;
  gemm_fullN<4>(a.A[z], a.Wt[z], a.b[z], a.C[z], HDIM, a.add, z==0?0:256);
}
__global__ __launch_bounds__(512) void k_gemm_proj(const u16* __restrict__ Ab,
                                                   const u16* __restrict__ Wt,
                                                   const float* __restrict__ b,
                                                   float* __restrict__ C){
  gemm_fullN<3>(Ab, Wt, b, C, HDIM);
}

// ======== mp GEMM with fused residual (+LayerNorm for z=0) epilogue (layers 0..L-2) ========
struct MpLnArgs { const u16* A[2]; const u16* Wt[2]; const float* b[2]; const u16* add;
                  float* st32[2]; u16* st16[2]; const float* lng; const float* lnb; };
__global__ __launch_bounds__(512) void k_gemm_mp_ln(MpLnArgs a){
  __shared__ __align__(16) u16 As[128*64];
  __shared__ __align__(16) u16 Bs[256*64];
  __shared__ float2 part[4][128];
  int z = blockIdx.z;
  const u16* A = a.A[z];
  const u16* Bt = a.Wt[z];
  const float* bias = a.b[z];
  const u16* add = a.add;
  float* st = a.st32[z];
  u16* stb = a.st16[z];
  int tid = threadIdx.x;
  int lane = tid & 63, wid = tid >> 6;
  int wm = wid & 1, wn = wid >> 1;
  int m0 = blockIdx.y * 128;
  const size_t Kb = 512;
  f32x4 acc[4][4] = {};
  for(int k0=0;k0<256;k0+=64){
    #pragma unroll
    for(int it=0; it<2; it++){
      int ci = it*512 + tid;
      int row = ci>>3, cl = ci&7;
      int csw = cl ^ (row&7);
      size_t go = (size_t)(m0+row)*Kb + (size_t)k0*2 + csw*16;
      gload_lds16((const char*)A+go, (char*)As + it*8192 + wid*1024);
    }
    #pragma unroll
    for(int it=0; it<4; it++){
      int ci = it*512 + tid;
      int row = ci>>3, cl = ci&7;
      int csw = cl ^ (row&7);
      size_t go = (size_t)row*Kb + (size_t)k0*2 + csw*16;
      gload_lds16((const char*)Bt+go, (char*)Bs + it*8192 + wid*1024);
    }
    __syncthreads();
    #pragma unroll
    for(int ks=0;ks<2;ks++){
      short8v av[4], bv[4];
      #pragma unroll
      for(int fm=0;fm<4;fm++){
        int m = wm*64 + fm*16 + (lane&15);
        int ch = (ks*4 + (lane>>4)) ^ (m&7);
        av[fm] = *(const short8v*)&As[m*64 + ch*8];
      }
      #pragma unroll
      for(int fn=0;fn<4;fn++){
        int n = wn*64 + fn*16 + (lane&15);
        int ch = (ks*4 + (lane>>4)) ^ (n&7);
        bv[fn] = *(const short8v*)&Bs[n*64 + ch*8];
      }
      #pragma unroll
      for(int fm=0;fm<4;fm++)
        #pragma unroll
        for(int fn=0;fn<4;fn++)
          acc[fm][fn] = __builtin_amdgcn_mfma_f32_16x16x32_bf16(av[fm], bv[fn], acc[fm][fn],0,0,0);
    }
    __syncthreads();
  }
  int ro=(lane>>4)*4, co=lane&15;
  int aoff = z ? 256 : 0;
  float bcol[4];
  #pragma unroll
  for(int fn=0;fn<4;fn++) bcol[fn] = bias[wn*64+fn*16+co];
  if(z==1){
    #pragma unroll
    for(int fm=0;fm<4;fm++){
      #pragma unroll
      for(int fn=0;fn<4;fn++){
        int col = wn*64+fn*16+co;
        #pragma unroll
        for(int r=0;r<4;r++){
          int row = m0 + wm*64 + fm*16 + ro + r;
          size_t ci = (size_t)row*256 + col;
          float o = acc[fm][fn][r] + bcol[fn] + bf2f(add[(size_t)row*512 + aoff + col]) + st[ci];
          st[ci] = o; stb[ci] = f2bf(o);
        }
      }
    }
    return;
  }
  // z==0: residual + LayerNorm
  float gv[4], bv2[4];
  #pragma unroll
  for(int fn=0;fn<4;fn++){ int col=wn*64+fn*16+co; gv[fn]=a.lng[col]; bv2[fn]=a.lnb[col]; }
  #pragma unroll
  for(int fm=0;fm<4;fm++){
    #pragma unroll
    for(int r=0;r<4;r++){
      int row = m0 + wm*64 + fm*16 + ro + r;
      float s1=0.f, s2=0.f;
      #pragma unroll
      for(int fn=0;fn<4;fn++){
        int col = wn*64+fn*16+co;
        float v = acc[fm][fn][r] + bcol[fn] + bf2f(add[(size_t)row*512 + col]) + st[(size_t)row*256 + col];
        acc[fm][fn][r] = v;
        s1 += v; s2 += v*v;
      }
      #pragma unroll
      for(int off=8; off; off>>=1){ s1 += __shfl_xor(s1,off,64); s2 += __shfl_xor(s2,off,64); }
      if(co==0){ float2 p; p.x=s1; p.y=s2; part[wn][wm*64+fm*16+ro+r] = p; }
    }
  }
  __syncthreads();
  #pragma unroll
  for(int fm=0;fm<4;fm++){
    #pragma unroll
    for(int r=0;r<4;r++){
      int rl = wm*64+fm*16+ro+r;
      float2 p0=part[0][rl], p1=part[1][rl], p2=part[2][rl], p3=part[3][rl];
      float s1 = p0.x+p1.x+p2.x+p3.x;
      float s2 = p0.y+p1.y+p2.y+p3.y;
      float mu = s1*(1.f/256.f);
      float var = s2*(1.f/256.f) - mu*mu;
      float rs = rsqrtf(var + 1e-5f);
      int row = m0 + rl;
      #pragma unroll
      for(int fn=0;fn<4;fn++){
        int col = wn*64+fn*16+co;
        size_t ci = (size_t)row*256 + col;
        float o = (acc[fm][fn][r]-mu)*rs*gv[fn] + bv2[fn];
        st[ci] = o; stb[ci] = f2bf(o);
      }
    }
  }
}

// ======== PAIR GEMM for QKV, BN=128 (64KB LDS -> 2 blocks/CU) + sincos epilogue ========
// grid (2, N/128, 3). waves 2(M)x4(N), wave tile 64x32.
struct Qkv3Args { const u16* Wm[3]; const u16* Wp[3]; u16* qpk; u16* kvpk; };
__global__ __launch_bounds__(512) void k_gemm_qkv3(const u16* __restrict__ magb,
                                                   const u16* __restrict__ phb,
                                                   Qkv3Args a){
  __shared__ __align__(16) u16 Ams[128*64];
  __shared__ __align__(16) u16 Aps[128*64];
  __shared__ __align__(16) u16 Bms[128*64];
  __shared__ __align__(16) u16 Bps[128*64];
  int z = blockIdx.z;
  const u16* Wmz = a.Wm[z];
  const u16* Wpz = a.Wp[z];
  int tid = threadIdx.x;
  int lane = tid & 63, wid = tid >> 6;
  int wm = wid & 1, wn = wid >> 1;      // wn in 0..3, wave tile 64x32
  int m0 = blockIdx.y * 128;
  int n0 = blockIdx.x * 128;
  const size_t Kb = 512;  // K=256 bf16
  f32x4 accm[4][2] = {}, accp[4][2] = {};
  for(int k0=0;k0<256;k0+=64){
    #pragma unroll
    for(int it=0; it<2; it++){
      int ci = it*512 + tid;
      int row = ci>>3, cl = ci&7;
      int csw = cl ^ (row&7);
      size_t goA = (size_t)(m0+row)*Kb + (size_t)k0*2 + csw*16;
      size_t goB = (size_t)(n0+row)*Kb + (size_t)k0*2 + csw*16;
      gload_lds16((const char*)magb+goA, (char*)Ams + it*8192 + wid*1024);
      gload_lds16((const char*)phb +goA, (char*)Aps + it*8192 + wid*1024);
      gload_lds16((const char*)Wmz +goB, (char*)Bms + it*8192 + wid*1024);
      gload_lds16((const char*)Wpz +goB, (char*)Bps + it*8192 + wid*1024);
    }
    __syncthreads();
    #pragma unroll
    for(int ks=0;ks<2;ks++){
      short8v am[4], ap[4], bm_[2], bp_[2];
      #pragma unroll
      for(int fm=0;fm<4;fm++){
        int m = wm*64 + fm*16 + (lane&15);
        int ch = (ks*4 + (lane>>4)) ^ (m&7);
        am[fm] = *(const short8v*)&Ams[m*64 + ch*8];
        ap[fm] = *(const short8v*)&Aps[m*64 + ch*8];
      }
      #pragma unroll
      for(int fn=0;fn<2;fn++){
        int n = wn*32 + fn*16 + (lane&15);
        int ch = (ks*4 + (lane>>4)) ^ (n&7);
        bm_[fn] = *(const short8v*)&Bms[n*64 + ch*8];
        bp_[fn] = *(const short8v*)&Bps[n*64 + ch*8];
      }
      #pragma unroll
      for(int fm=0;fm<4;fm++)
        #pragma unroll
        for(int fn=0;fn<2;fn++){
          accm[fm][fn] = __builtin_amdgcn_mfma_f32_16x16x32_bf16(am[fm], bm_[fn], accm[fm][fn],0,0,0);
          accp[fm][fn] = __builtin_amdgcn_mfma_f32_16x16x32_bf16(ap[fm], bp_[fn], accp[fm][fn],0,0,0);
        }
    }
    __syncthreads();
  }
  int ro=(lane>>4)*4, co=lane&15;
  #pragma unroll
  for(int fm=0;fm<4;fm++){
    #pragma unroll
    for(int fn=0;fn<2;fn++){
      int col = n0 + wn*32 + fn*16 + co;
      #pragma unroll
      for(int r=0;r<4;r++){
        int row = m0 + wm*64 + fm*16 + ro + r;
        float mv = accm[fm][fn][r];
        float pv = accp[fm][fn][r];
        u16 o0, o1;
        if(z<2){
          float sn, cs;
          __sincosf(pv, &sn, &cs);
          o0 = f2bf(mv*cs); o1 = f2bf(mv*sn);
        } else {
          o0 = f2bf(mv); o1 = f2bf(pv);
        }
        u16* base = (z==0) ? (a.qpk + (size_t)row*512)
                           : (a.kvpk + (size_t)row*1024 + (z==2 ? 512 : 0));
        base[col] = o0;
        base[col+256] = o1;
      }
    }
  }
}

// ---------------- fused attention v4: 4 edge-streams/wave, 16 lanes x 16 ch ----------------
__global__ __launch_bounds__(256) void k_attn_fused(
    const int* __restrict__ rowptr, const int* __restrict__ srcp,
    const u16* __restrict__ qpack, const u16* __restrict__ kvpack,
    const u16* __restrict__ rbfp,
    const float* __restrict__ We, const float* __restrict__ be,
    u16* __restrict__ npack)
{
  int wid = threadIdx.x >> 6, lane = threadIdx.x & 63;
  int gid = lane >> 4, l = lane & 15;
  int d = blockIdx.x*4 + wid;
  int b = rowptr[d], e = rowptr[d+1];
  const u16* qb = qpack + (size_t)d*512 + l*16;
  u16x8 qc0 = *(const u16x8*)qb;
  u16x8 qc1 = *(const u16x8*)(qb+8);
  u16x8 qs0 = *(const u16x8*)(qb+256);
  u16x8 qs1 = *(const u16x8*)(qb+264);
  float qcf[16], qsf[16];
  #pragma unroll
  for(int j=0;j<8;j++){
    qcf[j]=bf2f(qc0[j]); qcf[j+8]=bf2f(qc1[j]);
    qsf[j]=bf2f(qs0[j]); qsf[j+8]=bf2f(qs1[j]);
  }
  float Wef[4];
  #pragma unroll
  for(int k=0;k<4;k++) Wef[k] = (l*4+k < NRBF) ? We[l*4+k] : 0.f;
  float be0 = be[0];
  float z = 0.f;
  float avm[16], avp[16];
  #pragma unroll
  for(int j=0;j<16;j++){ avm[j]=0.f; avp[j]=0.f; }
  for(int i = b + gid; i < e; i += 4){
    int s = srcp[i];
    const u16* kb = kvpack + (size_t)s*1024 + l*16;
    u16x8 kc0 = *(const u16x8*)kb;
    u16x8 kc1 = *(const u16x8*)(kb+8);
    u16x8 ks0 = *(const u16x8*)(kb+256);
    u16x8 ks1 = *(const u16x8*)(kb+264);
    u16x8 vm0 = *(const u16x8*)(kb+512);
    u16x8 vm1 = *(const u16x8*)(kb+520);
    u16x8 vp0 = *(const u16x8*)(kb+768);
    u16x8 vp1 = *(const u16x8*)(kb+776);
    u16x4 rb4 = *(const u16x4*)(rbfp + (size_t)i*64 + l*4);
    float p = 0.f;
    #pragma unroll
    for(int j=0;j<8;j++){
      p = fmaf(qcf[j],   bf2f(kc0[j]), p);
      p = fmaf(qcf[j+8], bf2f(kc1[j]), p);
      p = fmaf(qsf[j],   bf2f(ks0[j]), p);
      p = fmaf(qsf[j+8], bf2f(ks1[j]), p);
    }
    float t = p*0.0625f;
    #pragma unroll
    for(int k=0;k<4;k++) t = fmaf(bf2f(rb4[k]), Wef[k], t);
    #pragma unroll
    for(int off=8; off; off>>=1) t += __shfl_xor(t, off, 64);
    float w = __expf(t + be0);   // scores O(1): softmax shift-invariant
    z += w;
    #pragma unroll
    for(int j=0;j<8;j++){
      avm[j]   = fmaf(w, bf2f(vm0[j]), avm[j]);
      avm[j+8] = fmaf(w, bf2f(vm1[j]), avm[j+8]);
      avp[j]   = fmaf(w, bf2f(vp0[j]), avp[j]);
      avp[j+8] = fmaf(w, bf2f(vp1[j]), avp[j+8]);
    }
  }
  z += __shfl_xor(z, 16, 64);
  z += __shfl_xor(z, 32, 64);
  #pragma unroll
  for(int j=0;j<16;j++){
    avm[j] += __shfl_xor(avm[j], 16, 64);
    avm[j] += __shfl_xor(avm[j], 32, 64);
    avp[j] += __shfl_xor(avp[j], 16, 64);
    avp[j] += __shfl_xor(avp[j], 32, 64);
  }
  if(gid==0){
    float inv = 1.f/(z + 1e-9f);
    u16x8 m0, m1, p0, p1;
    #pragma unroll
    for(int j=0;j<8;j++){
      m0[j]=f2bf(avm[j]*inv); m1[j]=f2bf(avm[j+8]*inv);
      p0[j]=f2bf(avp[j]*inv); p1[j]=f2bf(avp[j+8]*inv);
    }
    u16* nb = npack + (size_t)d*512 + l*16;
    *(u16x8*)nb = m0;       *(u16x8*)(nb+8)   = m1;
    *(u16x8*)(nb+256) = p0; *(u16x8*)(nb+264) = p1;
  }
}

// ---------------- message passing aggregation v5 (fp8 gate, 4 streams) ----------------
__global__ __launch_bounds__(256) void k_mp_agg(const int* __restrict__ rowptr,
                         const int* __restrict__ srcp, const unsigned char* __restrict__ gate,
                         const u16* __restrict__ npack,
                         u16* __restrict__ aggm, u16* __restrict__ aggp){
  int wid = threadIdx.x >> 6, lane = threadIdx.x & 63;
  int gid = lane >> 4, l = lane & 15;
  int n = blockIdx.x*4 + wid;
  int b = rowptr[n], e = rowptr[n+1];
  float am[16], ap[16];
  #pragma unroll
  for(int j=0;j<16;j++){ am[j]=0.f; ap[j]=0.f; }
  for(int i = b + gid; i < e; i += 4){
    int s = srcp[i];
    u8x16 g16 = *(const u8x16*)(gate + (size_t)i*256 + l*16);
    const u16* nb = npack + (size_t)s*512 + l*16;
    u16x8 m0 = *(const u16x8*)nb;
    u16x8 m1 = *(const u16x8*)(nb+8);
    u16x8 p0 = *(const u16x8*)(nb+256);
    u16x8 p1 = *(const u16x8*)(nb+264);
    #pragma unroll
    for(int j=0;j<8;j++){
      float ga = e42f(g16[j]), gb2 = e42f(g16[j+8]);
      am[j]   = fmaf(ga,  bf2f(m0[j]), am[j]);
      am[j+8] = fmaf(gb2, bf2f(m1[j]), am[j+8]);
      ap[j]   = fmaf(ga,  bf2f(p0[j]), ap[j]);
      ap[j+8] = fmaf(gb2, bf2f(p1[j]), ap[j+8]);
    }
  }
  #pragma unroll
  for(int j=0;j<16;j++){
    am[j] += __shfl_xor(am[j], 16, 64);
    am[j] += __shfl_xor(am[j], 32, 64);
    ap[j] += __shfl_xor(ap[j], 16, 64);
    ap[j] += __shfl_xor(ap[j], 32, 64);
  }
  if(gid==0){
    u16x8 a0, a1, b0, b1;
    #pragma unroll
    for(int j=0;j<8;j++){
      a0[j]=f2bf(am[j]); a1[j]=f2bf(am[j+8]);
      b0[j]=f2bf(ap[j]); b1[j]=f2bf(ap[j+8]);
    }
    size_t o = (size_t)n*256 + l*16;
    *(u16x8*)(aggm + o) = a0; *(u16x8*)(aggm + o + 8) = a1;
    *(u16x8*)(aggp + o) = b0; *(u16x8*)(aggp + o + 8) = b1;
  }
}

// ---------------- residual + LayerNorm, last layer (fuses mag*cos(ph) projection input) ----
__global__ __launch_bounds__(256) void k_resid_ln_last(const float* __restrict__ nmag, const float* __restrict__ nph,
                           const float* __restrict__ mag, const float* __restrict__ ph,
                           u16* __restrict__ tcosb,
                           const float* __restrict__ g, const float* __restrict__ b){
  int n = blockIdx.x, tid = threadIdx.x;
  size_t idx = (size_t)n*HDIM+tid;
  float t = nmag[idx] + mag[idx];
  float s1=t, s2=t*t;
  #pragma unroll
  for(int off=32; off; off>>=1){ s1 += __shfl_down(s1,off,64); s2 += __shfl_down(s2,off,64); }
  __shared__ float w1[4], w2[4], bc[2];
  int wid = tid>>6, lane = tid&63;
  if(lane==0){ w1[wid]=s1; w2[wid]=s2; }
  __syncthreads();
  if(tid==0){
    float a=w1[0]+w1[1]+w1[2]+w1[3];
    float q=w2[0]+w2[1]+w2[2]+w2[3];
    float mu = a*(1.f/HDIM);
    float var = q*(1.f/HDIM) - mu*mu;
    bc[0]=mu; bc[1]=rsqrtf(var+1e-5f);
  }
  __syncthreads();
  float mu=bc[0], rs=bc[1];
  float ln = (t-mu)*rs*g[tid]+b[tid];
  float p2 = nph[idx] + ph[idx];
  tcosb[idx] = f2bf(ln*__cosf(p2));
}

// ---------------- pooling ----------------
__global__ void k_pool(const float* __restrict__ arepr, const int* __restrict__ n2m,
                       float* __restrict__ spool, float* __restrict__ cntf){
  int gid = blockIdx.x*256+threadIdx.x;
  int n = gid>>8, h = gid&255;
  int m = n2m[n];
  atomicAdd(&spool[(size_t)m*HDIM+h], arepr[(size_t)n*HDIM+h]);
  if(h==0) atomicAdd(&cntf[m], 1.f);
}

// ---------------- head MLP ----------------
__global__ __launch_bounds__(256) void k_head(const float* __restrict__ spool, const float* __restrict__ cntf,
                       const float* __restrict__ W1, const float* __restrict__ b1,
                       const float* __restrict__ W2, const float* __restrict__ b2,
                       const float* __restrict__ W3, const float* __restrict__ b3,
                       float* __restrict__ out){
  __shared__ float smol[2*HDIM];
  __shared__ float sh1[HDIM];
  __shared__ float sh2[HDIM/2];
  int m = blockIdx.x, tid = threadIdx.x;
  float sv = spool[(size_t)m*HDIM+tid];
  float c = cntf[m];
  smol[tid] = sv/fmaxf(c,1.f);
  smol[HDIM+tid] = sv;
  __syncthreads();
  float a = b1[tid];
  for(int i=0;i<2*HDIM;i++) a = fmaf(smol[i], W1[i*HDIM+tid], a);
  sh1[tid] = siluf(a);
  __syncthreads();
  if(tid<128){
    float a2 = b2[tid];
    for(int i=0;i<HDIM;i++) a2 = fmaf(sh1[i], W2[i*128+tid], a2);
    sh2[tid] = siluf(a2);
  }
  __syncthreads();
  if(tid<64){
    float p = sh2[tid]*W3[tid] + sh2[tid+64]*W3[tid+64];
    #pragma unroll
    for(int off=32; off; off>>=1) p += __shfl_down(p,off,64);
    if(tid==0) out[m] = p + b3[0];
  }
}

extern "C" void kernel_launch(void* const* d_in, const int* in_sizes, int n_in,
                              void* d_out, int out_size, void* d_ws, size_t ws_size,
                              hipStream_t stream){
  const float* atom_types = (const float*)d_in[0];
  const float* coords     = (const float*)d_in[1];
  const float* edge_dist  = (const float*)d_in[2];
  const int*   edge_index = (const int*)d_in[3];
  const int*   node2mol   = (const int*)d_in[4];
  const float* emb_Wm = (const float*)d_in[5];
  const float* emb_bm = (const float*)d_in[6];
  const float* emb_Wp = (const float*)d_in[7];
  const float* emb_bp = (const float*)d_in[8];
  const float* attn_Wqm = (const float*)d_in[9];
  const float* attn_Wkm = (const float*)d_in[10];
  const float* attn_Wvm = (const float*)d_in[11];
  const float* attn_Wqp = (const float*)d_in[12];
  const float* attn_Wkp = (const float*)d_in[13];
  const float* attn_Wvp = (const float*)d_in[14];
  const float* attn_We  = (const float*)d_in[15];
  const float* attn_be  = (const float*)d_in[16];
  const float* mp_We = (const float*)d_in[17];
  const float* mp_be = (const float*)d_in[18];
  const float* mp_Wm = (const float*)d_in[19];
  const float* mp_bm = (const float*)d_in[20];
  const float* mp_Wp = (const float*)d_in[21];
  const float* mp_bp = (const float*)d_in[22];
  const float* ln_g = (const float*)d_in[23];
  const float* ln_b = (const float*)d_in[24];
  const float* proj_W = (const float*)d_in[25];
  const float* proj_b = (const float*)d_in[26];
  const float* head_W1 = (const float*)d_in[27];
  const float* head_b1 = (const float*)d_in[28];
  const float* head_W2 = (const float*)d_in[29];
  const float* head_b2 = (const float*)d_in[30];
  const float* head_W3 = (const float*)d_in[31];
  const float* head_b3 = (const float*)d_in[32];
  float* out = (float*)d_out;

  float* ws = (float*)d_ws;
  const size_t NH = (size_t)N_NODES*HDIM;
  size_t o = 0;
  float* mag = ws + o; o += NH;
  float* ph  = ws + o; o += NH;
  float* nmag= ws + o; o += NH;
  float* nph = ws + o; o += NH;
  float* spool = ws + o; o += (size_t)N_MOLS*HDIM;
  float* cntf  = ws + o; o += N_MOLS;
  int* rowptr = (int*)(ws + o); o += N_NODES+1;
  int* cnt    = (int*)(ws + o); o += N_NODES;
  int* cursor = (int*)(ws + o); o += N_NODES;
  int* perm   = (int*)(ws + o); o += N_EDGES;
  int* srcp   = (int*)(ws + o); o += N_EDGES + 1;   // +1 keeps 8B alignment after
  u16* magb = (u16*)(ws + o); o += NH/2;
  u16* phb  = (u16*)(ws + o); o += NH/2;
  u16* aggmb= (u16*)(ws + o); o += NH/2;
  u16* aggpb= (u16*)(ws + o); o += NH/2;
  u16* npack= (u16*)(ws + o); o += NH;                        // [N][512] bf16 (mag|ph)
  u16* rbfp = (u16*)(ws + o); o += (size_t)N_EDGES*32;        // [E][64] bf16, CSR order
  u16* qpack= (u16*)(ws + o); o += NH;                        // [N][512] bf16 (qc|qs)
  u16* kvpack=(u16*)(ws + o); o += 2*NH;                      // [N][1024] bf16 (kc|ks|vm|vp)
  o += NH;                                                    // pad: gatep tail
  u16* wt   = (u16*)(ws + o); o += (25*(size_t)HH + 3*HDIM*64)/2;
  unsigned char* gatep = (unsigned char*)qpack;  // [E][256] fp8 CSR order (disjoint lifetime)
  float* arepr = nmag;     // free after last resid_ln
  u16* tcosb = aggmb;      // free after last mp gemm

  const int* src = edge_index;
  const int* dst = edge_index + N_EDGES;

  // ---- weight convert/transpose descriptors ----
  WArgs wa;
  for(int l=0;l<NLAYER;l++){
    const float* srcs[6] = {attn_Wqm+(size_t)l*HH, attn_Wkm+(size_t)l*HH, attn_Wvm+(size_t)l*HH,
                            attn_Wqp+(size_t)l*HH, attn_Wkp+(size_t)l*HH, attn_Wvp+(size_t)l*HH};
    for(int j=0;j<6;j++){ wa.d[l*6+j] = { srcs[j], wt + (size_t)(l*6+j)*HH, HDIM, HDIM }; }
    wa.d[18+l] = { mp_Wm+(size_t)l*HH, wt + (size_t)(18+l)*HH, HDIM, HDIM };
    wa.d[21+l] = { mp_Wp+(size_t)l*HH, wt + (size_t)(21+l)*HH, HDIM, HDIM };
    wa.d[25+l] = { mp_We+(size_t)l*NRBF*HDIM, wt + (size_t)25*HH + (size_t)l*HDIM*64, NRBF, 64 };
  }
  wa.d[24] = { proj_W, wt + (size_t)24*HH, HDIM, HDIM };

  hipMemsetAsync(cnt, 0, N_NODES*sizeof(int), stream);
  k_hist<<<N_EDGES/256,256,0,stream>>>(dst, cnt);
  k_scan<<<1,1024,0,stream>>>(cnt, rowptr, cursor);
  k_scatter<<<N_EDGES/256,256,0,stream>>>(dst, src, cursor, perm, srcp);
  k_wconv<<<dim3(28,64),256,0,stream>>>(wa);
  k_rbf<<<(N_EDGES*64)/256,256,0,stream>>>(edge_dist, perm, rbfp);
  k_embed<<<N_NODES,256,0,stream>>>(atom_types, coords, emb_Wm, emb_bm, emb_Wp, emb_bp,
                                    mag, ph, magb, phb);

  for(int l=0;l<NLAYER;l++){
    Qkv3Args qa;
    qa.Wm[0] = wt + (size_t)(l*6+0)*HH;  // Wqm
    qa.Wm[1] = wt + (size_t)(l*6+1)*HH;  // Wkm
    qa.Wm[2] = wt + (size_t)(l*6+2)*HH;  // Wvm
    qa.Wp[0] = wt + (size_t)(l*6+3)*HH;  // Wqp
    qa.Wp[1] = wt + (size_t)(l*6+4)*HH;  // Wkp
    qa.Wp[2] = wt + (size_t)(l*6+5)*HH;  // Wvp
    qa.qpk = qpack; qa.kvpk = kvpack;
    k_gemm_qkv3<<<dim3(2,N_NODES/128,3),512,0,stream>>>(magb, phb, qa);
    k_attn_fused<<<N_NODES/4,256,0,stream>>>(rowptr, srcp, qpack, kvpack,
                                             rbfp, attn_We+(size_t)l*NRBF, attn_be+l,
                                             npack);
    k_gemm_gate<<<dim3(1,N_EDGES/128),512,0,stream>>>(rbfp, wt + (size_t)25*HH + (size_t)l*HDIM*64,
                                                      mp_be+(size_t)l*HDIM, gatep);
    k_mp_agg<<<N_NODES/4,256,0,stream>>>(rowptr, srcp, gatep, npack, aggmb, aggpb);
    if(l < NLAYER-1){
      MpLnArgs ml;
      ml.A[0]=aggmb; ml.A[1]=aggpb;
      ml.Wt[0]=wt + (size_t)(18+l)*HH; ml.Wt[1]=wt + (size_t)(21+l)*HH;
      ml.b[0]=mp_bm+(size_t)l*HDIM; ml.b[1]=mp_bp+(size_t)l*HDIM;
      ml.add = npack;
      ml.st32[0]=mag; ml.st32[1]=ph; ml.st16[0]=magb; ml.st16[1]=phb;
      ml.lng = ln_g+(size_t)l*HDIM; ml.lnb = ln_b+(size_t)l*HDIM;
      k_gemm_mp_ln<<<dim3(1,N_NODES/128,2),512,0,stream>>>(ml);
    } else {
      MpArgs ma;
      ma.A[0]=aggmb; ma.A[1]=aggpb;
      ma.Wt[0]=wt + (size_t)(18+l)*HH; ma.Wt[1]=wt + (size_t)(21+l)*HH;
      ma.b[0]=mp_bm+(size_t)l*HDIM; ma.b[1]=mp_bp+(size_t)l*HDIM;
      ma.C[0]=nmag; ma.C[1]=nph;
      ma.add = npack;
      k_gemm_mp<<<dim3(1,N_NODES/128,2),512,0,stream>>>(ma);
      k_resid_ln_last<<<N_NODES,256,0,stream>>>(nmag, nph, mag, ph, tcosb,
                                                ln_g+(size_t)l*HDIM, ln_b+(size_t)l*HDIM);
    }
  }
  k_gemm_proj<<<dim3(1,N_NODES/128),512,0,stream>>>(tcosb, wt + (size_t)24*HH, proj_b, arepr);
  hipMemsetAsync(spool, 0, ((size_t)N_MOLS*HDIM+N_MOLS)*sizeof(float), stream);
  k_pool<<<NH/256,256,0,stream>>>(arepr, node2mol, spool, cntf);
  k_head<<<N_MOLS,256,0,stream>>>(spool, cntf, head_W1, head_b1, head_W2, head_b2, head_W3, head_b3, out);
}